// Round 1
// baseline (1950.586 us; speedup 1.0000x reference)
//
#include <hip/hip_runtime.h>
#include <cfloat>
#include <cstdint>

// VQ-VAE vector quantizer forward, fp32 baseline.
//   B=16, D=512, H=W=32 -> NTOK=16384 tokens; CD=256, K=8192 codes.
// out[0]: [16,512,32,32] f32 (8388608), out[1]: indices [16,1024] as f32 (16384),
// out[2]: commitment loss scalar (1).  All concatenated flat in d_out (float32).

#define B_      16
#define DIN     512
#define HW      1024
#define CDIM    256
#define KCODES  8192
#define NTOK    (B_ * HW)            // 16384
#define OUT_ELEMS (B_ * DIN * HW)    // 8388608
#define GAP_EPS 1e-3f

// ---------------- K0: row sum-of-squares (one wave per 256-float row) ----------
__global__ __launch_bounds__(256) void k_rowsq(const float* __restrict__ rows,
                                               float* __restrict__ out, int nrows) {
  const int wid = (blockIdx.x * blockDim.x + threadIdx.x) >> 6;
  const int lane = threadIdx.x & 63;
  if (wid >= nrows) return;
  const float4 v = *(const float4*)(rows + (size_t)wid * CDIM + lane * 4);
  float s = v.x * v.x + v.y * v.y + v.z * v.z + v.w * v.w;
#pragma unroll
  for (int off = 32; off > 0; off >>= 1) s += __shfl_down(s, off, 64);
  if (lane == 0) out[wid] = s;
}

// ---------------- K1: z = x^T @ W_in^T + b_in  (64 tok x 64 col tiles) ---------
__global__ __launch_bounds__(256) void k_proj_in(const float* __restrict__ x,
                                                 const float* __restrict__ Win,
                                                 const float* __restrict__ bin,
                                                 float* __restrict__ z) {
  __shared__ float As[16][68];
  __shared__ float Ws[16][68];
  const int tok0 = blockIdx.x * 64;
  const int col0 = blockIdx.y * 64;
  const int b = tok0 / HW;
  const int n0 = tok0 % HW;
  const float* xb = x + (size_t)b * DIN * HW + n0;
  const int tid = threadIdx.x;
  const int tx = tid & 15, ty = tid >> 4;
  float acc[4][4] = {};
  for (int kb = 0; kb < DIN; kb += 16) {
    __syncthreads();
    {
      const int tok = tid & 63;
      const int kkb = tid >> 6;
#pragma unroll
      for (int r = 0; r < 4; ++r) {
        const int kk = r * 4 + kkb;
        As[kk][tok] = xb[(size_t)(kb + kk) * HW + tok];
      }
      const int col = tid >> 2;
      const int kq = (tid & 3) * 4;
      const float4 w4 = *(const float4*)(Win + (size_t)(col0 + col) * DIN + kb + kq);
      Ws[kq + 0][col] = w4.x; Ws[kq + 1][col] = w4.y;
      Ws[kq + 2][col] = w4.z; Ws[kq + 3][col] = w4.w;
    }
    __syncthreads();
#pragma unroll
    for (int kk = 0; kk < 16; ++kk) {
      const float4 wv = *(const float4*)&Ws[kk][tx * 4];
#pragma unroll
      for (int i = 0; i < 4; ++i) {
        const float a = As[kk][ty * 4 + i];
        acc[i][0] = fmaf(a, wv.x, acc[i][0]);
        acc[i][1] = fmaf(a, wv.y, acc[i][1]);
        acc[i][2] = fmaf(a, wv.z, acc[i][2]);
        acc[i][3] = fmaf(a, wv.w, acc[i][3]);
      }
    }
  }
  const float4 bias = *(const float4*)(bin + col0 + tx * 4);
#pragma unroll
  for (int i = 0; i < 4; ++i) {
    const int t = tok0 + ty * 4 + i;
    float4 o;
    o.x = acc[i][0] + bias.x; o.y = acc[i][1] + bias.y;
    o.z = acc[i][2] + bias.z; o.w = acc[i][3] + bias.w;
    *(float4*)(z + (size_t)t * CDIM + col0 + tx * 4) = o;
  }
}

// ---------------- K2: distance GEMM + per-half argmin -------------------------
// score s(t,k) = ||e_k||^2 - 2 z_t.e_k   (||z||^2 dropped: argmin-invariant,
// keeps comparisons at small magnitude for precision). Tracks best + 2nd-best
// value; near-ties rescored in fp64 by k_rescue. blockIdx.y selects K-half.
__global__ __launch_bounds__(256) void k_argmin(const float* __restrict__ z,
                                                const float* __restrict__ cb,
                                                const float* __restrict__ ee,
                                                float* __restrict__ pmv,
                                                int* __restrict__ pmi,
                                                float* __restrict__ psv) {
  __shared__ float Zs[64][260];        // 64 tok x 256 dims (+4 pad: 16B align, low conflict)
  __shared__ float Es0[16][68];        // codes c0..c0+63   (BK=16 dims)
  __shared__ float Es1[16][68];        // codes c0+64..c0+127
  const int tok0 = blockIdx.x * 64;
  const int cbase = blockIdx.y * (KCODES / 2);
  const int tid = threadIdx.x;
  const int tx = tid & 15, ty = tid >> 4;

  for (int u = tid; u < 64 * 64; u += 256) {
    const int tok = u >> 6;
    const int c4 = (u & 63) * 4;
    *(float4*)&Zs[tok][c4] = *(const float4*)(z + (size_t)(tok0 + tok) * CDIM + c4);
  }

  float mv[4], sv[4]; int mi[4];
#pragma unroll
  for (int i = 0; i < 4; ++i) { mv[i] = FLT_MAX; sv[i] = FLT_MAX; mi[i] = 0; }

  for (int c0 = cbase; c0 < cbase + KCODES / 2; c0 += 128) {
    float acc[4][8] = {};
    for (int kb = 0; kb < CDIM; kb += 16) {
      __syncthreads();
      {
        const int code = tid >> 1;           // 0..127
        const int kq = (tid & 1) * 8;
        const float* src = cb + (size_t)(c0 + code) * CDIM + kb + kq;
        const float4 v0 = *(const float4*)src;
        const float4 v1 = *(const float4*)(src + 4);
        float (*E)[68] = (code < 64) ? Es0 : Es1;
        const int cc = code & 63;
        E[kq + 0][cc] = v0.x; E[kq + 1][cc] = v0.y; E[kq + 2][cc] = v0.z; E[kq + 3][cc] = v0.w;
        E[kq + 4][cc] = v1.x; E[kq + 5][cc] = v1.y; E[kq + 6][cc] = v1.z; E[kq + 7][cc] = v1.w;
      }
      __syncthreads();
      float zrf[4][16];
#pragma unroll
      for (int i = 0; i < 4; ++i)
#pragma unroll
        for (int q = 0; q < 4; ++q) {
          const float4 v = *(const float4*)&Zs[ty * 4 + i][kb + q * 4];
          zrf[i][q * 4 + 0] = v.x; zrf[i][q * 4 + 1] = v.y;
          zrf[i][q * 4 + 2] = v.z; zrf[i][q * 4 + 3] = v.w;
        }
#pragma unroll
      for (int kk = 0; kk < 16; ++kk) {
        const float4 e0 = *(const float4*)&Es0[kk][tx * 4];
        const float4 e1 = *(const float4*)&Es1[kk][tx * 4];
#pragma unroll
        for (int i = 0; i < 4; ++i) {
          const float a = zrf[i][kk];
          acc[i][0] = fmaf(a, e0.x, acc[i][0]);
          acc[i][1] = fmaf(a, e0.y, acc[i][1]);
          acc[i][2] = fmaf(a, e0.z, acc[i][2]);
          acc[i][3] = fmaf(a, e0.w, acc[i][3]);
          acc[i][4] = fmaf(a, e1.x, acc[i][4]);
          acc[i][5] = fmaf(a, e1.y, acc[i][5]);
          acc[i][6] = fmaf(a, e1.z, acc[i][6]);
          acc[i][7] = fmaf(a, e1.w, acc[i][7]);
        }
      }
    }
    const float4 ev0 = *(const float4*)(ee + c0 + tx * 4);
    const float4 ev1 = *(const float4*)(ee + c0 + 64 + tx * 4);
    const float eb[8] = {ev0.x, ev0.y, ev0.z, ev0.w, ev1.x, ev1.y, ev1.z, ev1.w};
#pragma unroll
    for (int i = 0; i < 4; ++i) {
#pragma unroll
      for (int j = 0; j < 8; ++j) {
        const float s = fmaf(-2.0f, acc[i][j], eb[j]);
        const int code = c0 + (j < 4 ? tx * 4 + j : 64 + tx * 4 + (j - 4));
        if (s < mv[i]) { sv[i] = mv[i]; mv[i] = s; mi[i] = code; }
        else if (s < sv[i]) sv[i] = s;
      }
    }
  }
  // merge across the 16 tx lanes sharing each token quad (lanes grouped by 16)
#pragma unroll
  for (int off = 1; off < 16; off <<= 1) {
#pragma unroll
    for (int i = 0; i < 4; ++i) {
      const float ov = __shfl_xor(mv[i], off, 64);
      const int   oi = __shfl_xor(mi[i], off, 64);
      const float os = __shfl_xor(sv[i], off, 64);
      const float snew = fminf(fminf(sv[i], os), fmaxf(mv[i], ov));
      if (ov < mv[i] || (ov == mv[i] && oi < mi[i])) { mv[i] = ov; mi[i] = oi; }
      sv[i] = snew;
    }
  }
  if (tx == 0) {
#pragma unroll
    for (int i = 0; i < 4; ++i) {
      const int t = blockIdx.y * NTOK + tok0 + ty * 4 + i;
      pmv[t] = mv[i]; pmi[t] = mi[i]; psv[t] = sv[i];
    }
  }
}

// ---------------- K2b: merge the two K-halves, emit indices + rescue flags ----
__global__ __launch_bounds__(256) void k_merge(const float* __restrict__ pmv,
                                               const int* __restrict__ pmi,
                                               const float* __restrict__ psv,
                                               int* __restrict__ idxi,
                                               float* __restrict__ idx_f,
                                               int* __restrict__ flags) {
  const int t = blockIdx.x * 256 + threadIdx.x;
  const float v0 = pmv[t], v1 = pmv[NTOK + t];
  const int   i0 = pmi[t], i1 = pmi[NTOK + t];
  const float s0 = psv[t], s1 = psv[NTOK + t];
  const float snew = fminf(fminf(s0, s1), fmaxf(v0, v1));
  float mv = v0; int mi = i0;
  if (v1 < v0 || (v1 == v0 && i1 < i0)) { mv = v1; mi = i1; }
  idxi[t] = mi;
  idx_f[t] = (float)mi;
  flags[t] = (snew - mv < GAP_EPS) ? 1 : 0;
}

// ---------------- K2c: fp64 rescore of near-tie tokens (rare, ~tens) ----------
__global__ __launch_bounds__(256) void k_rescue(const float* __restrict__ z,
                                                const float* __restrict__ cb,
                                                const int* __restrict__ flags,
                                                int* __restrict__ idxi,
                                                float* __restrict__ idx_f) {
  const int t = blockIdx.x;
  if (flags[t] == 0) return;
  __shared__ float zrow[CDIM];
  __shared__ double svals[256];
  __shared__ int sidx[256];
  const int tid = threadIdx.x;
  zrow[tid] = z[(size_t)t * CDIM + tid];
  __syncthreads();
  double best = 1e300; int bi = 0;
  for (int k = tid; k < KCODES; k += 256) {
    const float* e = cb + (size_t)k * CDIM;
    double s = 0.0;
    for (int c = 0; c < CDIM; c += 4) {
      const double d0 = (double)zrow[c]     - (double)e[c];
      const double d1 = (double)zrow[c + 1] - (double)e[c + 1];
      const double d2 = (double)zrow[c + 2] - (double)e[c + 2];
      const double d3 = (double)zrow[c + 3] - (double)e[c + 3];
      s += d0 * d0 + d1 * d1 + d2 * d2 + d3 * d3;
    }
    if (s < best) { best = s; bi = k; }
  }
  svals[tid] = best; sidx[tid] = bi;
  __syncthreads();
  if (tid == 0) {
    double bv = svals[0]; int bx = sidx[0];
    for (int i = 1; i < 256; ++i)
      if (svals[i] < bv || (svals[i] == bv && sidx[i] < bx)) { bv = svals[i]; bx = sidx[i]; }
    idxi[t] = bx;
    idx_f[t] = (float)bx;
  }
}

// ---------------- K3: out = codebook[idx] @ W_out^T + b_out (transposed store) -
__global__ __launch_bounds__(256) void k_proj_out(const float* __restrict__ cb,
                                                  const int* __restrict__ idxi,
                                                  const float* __restrict__ Wout,
                                                  const float* __restrict__ bout,
                                                  float* __restrict__ out) {
  __shared__ float Qs[16][68];
  __shared__ float Ws[16][68];
  __shared__ int sidx[64];
  const int tok0 = blockIdx.x * 64;
  const int d0 = blockIdx.y * 64;
  const int tid = threadIdx.x;
  const int tx = tid & 15, ty = tid >> 4;   // tx -> token quad (coalesced store), ty -> d quad
  if (tid < 64) sidx[tid] = idxi[tok0 + tid];
  float acc[4][4] = {};                     // [i=d][j=tok]
  for (int kb = 0; kb < CDIM; kb += 16) {
    __syncthreads();
    {
      const int r = tid >> 2;
      const int kq = (tid & 3) * 4;
      const float4 q4 = *(const float4*)(cb + (size_t)sidx[r] * CDIM + kb + kq);
      Qs[kq + 0][r] = q4.x; Qs[kq + 1][r] = q4.y; Qs[kq + 2][r] = q4.z; Qs[kq + 3][r] = q4.w;
      const float4 w4 = *(const float4*)(Wout + (size_t)(d0 + r) * CDIM + kb + kq);
      Ws[kq + 0][r] = w4.x; Ws[kq + 1][r] = w4.y; Ws[kq + 2][r] = w4.z; Ws[kq + 3][r] = w4.w;
    }
    __syncthreads();
#pragma unroll
    for (int kk = 0; kk < 16; ++kk) {
      const float4 qv = *(const float4*)&Qs[kk][tx * 4];
#pragma unroll
      for (int i = 0; i < 4; ++i) {
        const float wv = Ws[kk][ty * 4 + i];
        acc[i][0] = fmaf(wv, qv.x, acc[i][0]);
        acc[i][1] = fmaf(wv, qv.y, acc[i][1]);
        acc[i][2] = fmaf(wv, qv.z, acc[i][2]);
        acc[i][3] = fmaf(wv, qv.w, acc[i][3]);
      }
    }
  }
  const int b = tok0 / HW;
  const int n0 = tok0 % HW;
  float* ob = out + (size_t)b * DIN * HW + n0;
#pragma unroll
  for (int i = 0; i < 4; ++i) {
    const int d = d0 + ty * 4 + i;
    const float bb = bout[d];
    float4 o;
    o.x = acc[i][0] + bb; o.y = acc[i][1] + bb;
    o.z = acc[i][2] + bb; o.w = acc[i][3] + bb;
    *(float4*)(ob + (size_t)d * HW + tx * 4) = o;
  }
}

// ---------------- K4: commitment loss = mean((q - z)^2), one wave per token ---
__global__ __launch_bounds__(256) void k_loss(const float* __restrict__ z,
                                              const float* __restrict__ cb,
                                              const int* __restrict__ idxi,
                                              float* __restrict__ loss) {
  const int wid = (blockIdx.x * blockDim.x + threadIdx.x) >> 6;
  const int lane = threadIdx.x & 63;
  const float4 zv = *(const float4*)(z + (size_t)wid * CDIM + lane * 4);
  const float4 qv = *(const float4*)(cb + (size_t)idxi[wid] * CDIM + lane * 4);
  const float dx = qv.x - zv.x, dy = qv.y - zv.y;
  const float dz2 = qv.z - zv.z, dw = qv.w - zv.w;
  float s = dx * dx + dy * dy + dz2 * dz2 + dw * dw;
#pragma unroll
  for (int off = 32; off > 0; off >>= 1) s += __shfl_down(s, off, 64);
  if (lane == 0) atomicAdd(loss, s * (1.0f / ((float)NTOK * (float)CDIM)));
}

extern "C" void kernel_launch(void* const* d_in, const int* in_sizes, int n_in,
                              void* d_out, int out_size, void* d_ws, size_t ws_size,
                              hipStream_t stream) {
  const float* x    = (const float*)d_in[0];
  const float* Win  = (const float*)d_in[1];
  const float* bin  = (const float*)d_in[2];
  const float* Wout = (const float*)d_in[3];
  const float* bout = (const float*)d_in[4];
  const float* cb   = (const float*)d_in[5];

  float* out   = (float*)d_out;
  float* idx_f = out + OUT_ELEMS;
  float* loss  = out + OUT_ELEMS + NTOK;

  char* w = (char*)d_ws;
  float* z     = (float*)w;                                   // 16 MB
  size_t off   = (size_t)NTOK * CDIM * 4;
  float* ee    = (float*)(w + off); off += (size_t)KCODES * 4;
  int*   idxi  = (int*)(w + off);   off += (size_t)NTOK * 4;
  int*   flags = (int*)(w + off);   off += (size_t)NTOK * 4;
  float* pmv   = (float*)(w + off); off += (size_t)2 * NTOK * 4;
  int*   pmi   = (int*)(w + off);   off += (size_t)2 * NTOK * 4;
  float* psv   = (float*)(w + off); off += (size_t)2 * NTOK * 4;

  hipMemsetAsync(loss, 0, sizeof(float), stream);

  k_rowsq   <<<dim3(KCODES / 4),          dim3(256), 0, stream>>>(cb, ee, KCODES);
  k_proj_in <<<dim3(NTOK / 64, CDIM / 64), dim3(256), 0, stream>>>(x, Win, bin, z);
  k_argmin  <<<dim3(NTOK / 64, 2),        dim3(256), 0, stream>>>(z, cb, ee, pmv, pmi, psv);
  k_merge   <<<dim3(NTOK / 256),          dim3(256), 0, stream>>>(pmv, pmi, psv, idxi, idx_f, flags);
  k_rescue  <<<dim3(NTOK),                dim3(256), 0, stream>>>(z, cb, flags, idxi, idx_f);
  k_proj_out<<<dim3(NTOK / 64, DIN / 64), dim3(256), 0, stream>>>(cb, idxi, Wout, bout, out);
  k_loss    <<<dim3(NTOK / 4),            dim3(256), 0, stream>>>(z, cb, idxi, loss);
}

// Round 3
// 1136.613 us; speedup vs baseline: 1.7161x; 1.7161x over previous
//
#include <hip/hip_runtime.h>
#include <cfloat>
#include <cstdint>

// VQ-VAE vector quantizer forward. Round 3: fix wn-race in MFMA argmin
// (waves covering same tokens / different code halves now emit separate
// partial strips; merge widened to 16).
#define B_      16
#define DIN     512
#define HW      1024
#define CDIM    256
#define KCODES  8192
#define NTOK    (B_ * HW)            // 16384
#define OUT_ELEMS (B_ * DIN * HW)    // 8388608
#define GAP_EPS 1e-3f
#define NSTRIP  8                    // K-strips across blockIdx.y
#define NPART   (NSTRIP * 2)         // partials per token (x2: wn halves)
#define CPS     (KCODES / NSTRIP)    // 1024 codes per strip

typedef __attribute__((ext_vector_type(8))) short bf16x8;
typedef __attribute__((ext_vector_type(4))) float f32x4;

static __device__ __forceinline__ short f2bf(float f) {
  unsigned u = __builtin_bit_cast(unsigned, f);
  u += 0x7FFFu + ((u >> 16) & 1u);           // RNE
  return (short)(u >> 16);
}
static __device__ __forceinline__ float bf2f(short h) {
  unsigned u = ((unsigned)(unsigned short)h) << 16;
  return __builtin_bit_cast(float, u);
}

#define GLL16(gsrc, ldst)                                                      \
  __builtin_amdgcn_global_load_lds(                                            \
      (const __attribute__((address_space(1))) unsigned int*)(gsrc),           \
      (__attribute__((address_space(3))) unsigned int*)(ldst), 16, 0, 0)

// ---------------- K0: codebook -> bf16 hi/lo + row sumsq ----------------------
__global__ __launch_bounds__(256) void k_prep_cb(const float* __restrict__ cb,
                                                 short* __restrict__ cb_hi,
                                                 short* __restrict__ cb_lo,
                                                 float* __restrict__ ee) {
  const int wid = (blockIdx.x * 256 + threadIdx.x) >> 6;   // code row
  const int lane = threadIdx.x & 63;
  const float4 v = *(const float4*)(cb + (size_t)wid * CDIM + lane * 4);
  float s = v.x * v.x + v.y * v.y + v.z * v.z + v.w * v.w;
  short4 h, l;
  h.x = f2bf(v.x); l.x = f2bf(v.x - bf2f(h.x));
  h.y = f2bf(v.y); l.y = f2bf(v.y - bf2f(h.y));
  h.z = f2bf(v.z); l.z = f2bf(v.z - bf2f(h.z));
  h.w = f2bf(v.w); l.w = f2bf(v.w - bf2f(h.w));
  *(short4*)(cb_hi + (size_t)wid * CDIM + lane * 4) = h;
  *(short4*)(cb_lo + (size_t)wid * CDIM + lane * 4) = l;
#pragma unroll
  for (int off = 32; off > 0; off >>= 1) s += __shfl_down(s, off, 64);
  if (lane == 0) ee[wid] = s;
}

// ---------------- K1: z = x^T @ W_in^T + b_in, emit z_hi/z_lo (bf16) ---------
__global__ __launch_bounds__(256) void k_proj_in(const float* __restrict__ x,
                                                 const float* __restrict__ Win,
                                                 const float* __restrict__ bin,
                                                 short* __restrict__ z_hi,
                                                 short* __restrict__ z_lo) {
  __shared__ float As[16][68];
  __shared__ float Ws[16][68];
  const int tok0 = blockIdx.x * 64;
  const int col0 = blockIdx.y * 64;
  const int b = tok0 / HW;
  const int n0 = tok0 % HW;
  const float* xb = x + (size_t)b * DIN * HW + n0;
  const int tid = threadIdx.x;
  const int tx = tid & 15, ty = tid >> 4;
  float acc[4][4] = {};
  for (int kb = 0; kb < DIN; kb += 16) {
    __syncthreads();
    {
      const int tok = tid & 63;
      const int kkb = tid >> 6;
#pragma unroll
      for (int r = 0; r < 4; ++r) {
        const int kk = r * 4 + kkb;
        As[kk][tok] = xb[(size_t)(kb + kk) * HW + tok];
      }
      const int col = tid >> 2;
      const int kq = (tid & 3) * 4;
      const float4 w4 = *(const float4*)(Win + (size_t)(col0 + col) * DIN + kb + kq);
      Ws[kq + 0][col] = w4.x; Ws[kq + 1][col] = w4.y;
      Ws[kq + 2][col] = w4.z; Ws[kq + 3][col] = w4.w;
    }
    __syncthreads();
#pragma unroll
    for (int kk = 0; kk < 16; ++kk) {
      const float4 wv = *(const float4*)&Ws[kk][tx * 4];
#pragma unroll
      for (int i = 0; i < 4; ++i) {
        const float a = As[kk][ty * 4 + i];
        acc[i][0] = fmaf(a, wv.x, acc[i][0]);
        acc[i][1] = fmaf(a, wv.y, acc[i][1]);
        acc[i][2] = fmaf(a, wv.z, acc[i][2]);
        acc[i][3] = fmaf(a, wv.w, acc[i][3]);
      }
    }
  }
  const float4 bias = *(const float4*)(bin + col0 + tx * 4);
#pragma unroll
  for (int i = 0; i < 4; ++i) {
    const int t = tok0 + ty * 4 + i;
    float o[4];
    o[0] = acc[i][0] + bias.x; o[1] = acc[i][1] + bias.y;
    o[2] = acc[i][2] + bias.z; o[3] = acc[i][3] + bias.w;
    short4 h, l;
    h.x = f2bf(o[0]); l.x = f2bf(o[0] - bf2f(h.x));
    h.y = f2bf(o[1]); l.y = f2bf(o[1] - bf2f(h.y));
    h.z = f2bf(o[2]); l.z = f2bf(o[2] - bf2f(h.z));
    h.w = f2bf(o[3]); l.w = f2bf(o[3] - bf2f(h.w));
    *(short4*)(z_hi + (size_t)t * CDIM + col0 + tx * 4) = h;
    *(short4*)(z_lo + (size_t)t * CDIM + col0 + tx * 4) = l;
  }
}

// ---------------- K2: MFMA distance GEMM + argmin (split-bf16, 3 products) ----
// s(t,k) = ||e_k||^2 - 2 z_t.e_k with z.e = zh.eh + zh.el + zl.eh (fp32 acc).
// 128x128 tile, BK=32, 4 waves of 64x64 (4x4 frags of mfma 16x16x32 bf16).
// LDS: Ah|Al|Bh|Bl, each 128 rows x 32 dims bf16 (8 KB), XOR-quad swizzled so
// global_load_lds (no padding possible) + ds_read_b128 frag reads are 2-way max.
// Each wave writes its OWN partial strip (strip = by*2 + wn): waves with same
// wm cover the same tokens but different code halves -> must not share a slot.
__global__ __launch_bounds__(256, 2) void k_argmin_mfma(
    const short* __restrict__ z_hi, const short* __restrict__ z_lo,
    const short* __restrict__ cb_hi, const short* __restrict__ cb_lo,
    const float* __restrict__ ee,
    float* __restrict__ pmv, int* __restrict__ pmi, float* __restrict__ psv) {
  __shared__ short lds_s[4 * 128 * 32];          // 32 KB
  char* ldsc = (char*)lds_s;
  const int tid = threadIdx.x;
  const int w = tid >> 6, lane = tid & 63;
  const int quad = lane >> 4, l16 = lane & 15;
  const int wm = w >> 1, wn = w & 1;
  const int tok0 = blockIdx.x * 128;
  const int cbase = blockIdx.y * CPS;

  // staging: slot u -> row t = u>>2, phys quad p = u&3, logical q = p^((t>>1)&3)
  const int uA = (w << 6) + lane;                // even issues (rows 0..63)
  const int uB = uA + 256;                       // odd issues (rows 64..127)
  const int tA = uA >> 2, pA = uA & 3, qA = pA ^ ((tA >> 1) & 3);
  const int tB = uB >> 2, pB = uB & 3, qB = pB ^ ((tB >> 1) & 3);
  const int offA = tA * CDIM + qA * 8;
  const int offB = tB * CDIM + qB * 8;
  const short* gAh0 = z_hi + (size_t)tok0 * CDIM + offA;
  const short* gAh1 = z_hi + (size_t)tok0 * CDIM + offB;
  const short* gAl0 = z_lo + (size_t)tok0 * CDIM + offA;
  const short* gAl1 = z_lo + (size_t)tok0 * CDIM + offB;

  // fragment LDS byte offsets (row = 64 B, swizzled quad)
  int aoffs[4], boffs[4];
#pragma unroll
  for (int mi = 0; mi < 4; ++mi) {
    const int t = wm * 64 + mi * 16 + l16;
    const int p = quad ^ ((t >> 1) & 3);
    aoffs[mi] = t * 64 + p * 16;
  }
#pragma unroll
  for (int ni = 0; ni < 4; ++ni) {
    const int t = wn * 64 + ni * 16 + l16;
    const int p = quad ^ ((t >> 1) & 3);
    boffs[ni] = 16384 + t * 64 + p * 16;         // Bh region base 16 KB
  }

  float mv[16], sv[16]; int bidx[16];
#pragma unroll
  for (int j = 0; j < 16; ++j) { mv[j] = FLT_MAX; sv[j] = FLT_MAX; bidx[j] = 0; }

  for (int ct = 0; ct < CPS / 128; ++ct) {
    const int ctile = cbase + ct * 128;
    const short* gBh0 = cb_hi + (size_t)ctile * CDIM + offA;
    const short* gBh1 = cb_hi + (size_t)ctile * CDIM + offB;
    const short* gBl0 = cb_lo + (size_t)ctile * CDIM + offA;
    const short* gBl1 = cb_lo + (size_t)ctile * CDIM + offB;
    f32x4 acc[4][4];
#pragma unroll
    for (int mi = 0; mi < 4; ++mi)
#pragma unroll
      for (int ni = 0; ni < 4; ++ni) acc[mi][ni] = (f32x4){0.f, 0.f, 0.f, 0.f};

    for (int kb = 0; kb < CDIM; kb += 32) {
      __syncthreads();                            // prior ds_reads done
      GLL16(gAh0 + kb, ldsc + ((0 * 4 + w) << 10));
      GLL16(gAh1 + kb, ldsc + ((1 * 4 + w) << 10));
      GLL16(gAl0 + kb, ldsc + ((2 * 4 + w) << 10));
      GLL16(gAl1 + kb, ldsc + ((3 * 4 + w) << 10));
      GLL16(gBh0 + kb, ldsc + ((4 * 4 + w) << 10));
      GLL16(gBh1 + kb, ldsc + ((5 * 4 + w) << 10));
      GLL16(gBl0 + kb, ldsc + ((6 * 4 + w) << 10));
      GLL16(gBl1 + kb, ldsc + ((7 * 4 + w) << 10));
      __syncthreads();                            // barrier drains vmcnt
      bf16x8 ah[4], al[4], bh[4], bl[4];
#pragma unroll
      for (int mi = 0; mi < 4; ++mi) {
        ah[mi] = *(const bf16x8*)(ldsc + aoffs[mi]);
        al[mi] = *(const bf16x8*)(ldsc + 8192 + aoffs[mi]);
      }
#pragma unroll
      for (int ni = 0; ni < 4; ++ni) {
        bh[ni] = *(const bf16x8*)(ldsc + boffs[ni]);
        bl[ni] = *(const bf16x8*)(ldsc + 8192 + boffs[ni]);
      }
#pragma unroll
      for (int mi = 0; mi < 4; ++mi)
#pragma unroll
        for (int ni = 0; ni < 4; ++ni) {
          f32x4 c = acc[mi][ni];
          c = __builtin_amdgcn_mfma_f32_16x16x32_bf16(ah[mi], bh[ni], c, 0, 0, 0);
          c = __builtin_amdgcn_mfma_f32_16x16x32_bf16(ah[mi], bl[ni], c, 0, 0, 0);
          c = __builtin_amdgcn_mfma_f32_16x16x32_bf16(al[mi], bh[ni], c, 0, 0, 0);
          acc[mi][ni] = c;
        }
    }
    // epilogue: s = ee - 2*dot ; C/D layout: col=l16 (code), row=quad*4+r (token)
    float eev[4];
#pragma unroll
    for (int ni = 0; ni < 4; ++ni) eev[ni] = ee[ctile + wn * 64 + ni * 16 + l16];
#pragma unroll
    for (int mi = 0; mi < 4; ++mi)
#pragma unroll
      for (int r = 0; r < 4; ++r) {
        const int j = mi * 4 + r;
#pragma unroll
        for (int ni = 0; ni < 4; ++ni) {
          const float s = fmaf(-2.0f, acc[mi][ni][r], eev[ni]);
          const int code = ctile + wn * 64 + ni * 16 + l16;
          if (s < mv[j]) { sv[j] = mv[j]; mv[j] = s; bidx[j] = code; }
          else if (s < sv[j]) sv[j] = s;
        }
      }
  }
  // merge across the 16 lanes (l16) holding different codes for same tokens
#pragma unroll
  for (int off = 1; off < 16; off <<= 1) {
#pragma unroll
    for (int j = 0; j < 16; ++j) {
      const float ov = __shfl_xor(mv[j], off, 64);
      const int   oi = __shfl_xor(bidx[j], off, 64);
      const float os = __shfl_xor(sv[j], off, 64);
      const float snew = fminf(fminf(sv[j], os), fmaxf(mv[j], ov));
      if (ov < mv[j] || (ov == mv[j] && oi < bidx[j])) { mv[j] = ov; bidx[j] = oi; }
      sv[j] = snew;
    }
  }
  if (l16 == 0) {
    const int strip = blockIdx.y * 2 + wn;       // wn halves get separate slots
#pragma unroll
    for (int j = 0; j < 16; ++j) {
      const int mi = j >> 2, r = j & 3;
      const int t = tok0 + wm * 64 + mi * 16 + quad * 4 + r;
      const size_t o = (size_t)strip * NTOK + t;
      pmv[o] = mv[j]; pmi[o] = bidx[j]; psv[o] = sv[j];
    }
  }
}

// ---------------- K2b: merge 16 partials, emit indices + rescue flags ---------
__global__ __launch_bounds__(256) void k_merge16(const float* __restrict__ pmv,
                                                 const int* __restrict__ pmi,
                                                 const float* __restrict__ psv,
                                                 int* __restrict__ idxi,
                                                 float* __restrict__ idx_f,
                                                 int* __restrict__ flags) {
  const int t = blockIdx.x * 256 + threadIdx.x;
  float mv = FLT_MAX, sv = FLT_MAX; int mi = 0x7fffffff;
#pragma unroll
  for (int s = 0; s < NPART; ++s) {
    const float v = pmv[(size_t)s * NTOK + t];
    const int   i = pmi[(size_t)s * NTOK + t];
    const float s2 = psv[(size_t)s * NTOK + t];
    if (v < mv || (v == mv && i < mi)) { sv = fminf(mv, s2); mv = v; mi = i; }
    else sv = fminf(sv, v);
  }
  idxi[t] = mi;
  idx_f[t] = (float)mi;
  flags[t] = (sv - mv < GAP_EPS) ? 1 : 0;
}

// ---------------- K2c: fp64 rescore of near-tie tokens (rare) -----------------
__global__ __launch_bounds__(256) void k_rescue(const short* __restrict__ z_hi,
                                                const short* __restrict__ z_lo,
                                                const float* __restrict__ cb,
                                                const int* __restrict__ flags,
                                                int* __restrict__ idxi,
                                                float* __restrict__ idx_f) {
  const int t = blockIdx.x;
  if (flags[t] == 0) return;
  __shared__ float zrow[CDIM];
  __shared__ double svals[256];
  __shared__ int sidx[256];
  const int tid = threadIdx.x;
  zrow[tid] = bf2f(z_hi[(size_t)t * CDIM + tid]) + bf2f(z_lo[(size_t)t * CDIM + tid]);
  __syncthreads();
  double best = 1e300; int bi = 0;
  for (int k = tid; k < KCODES; k += 256) {
    const float* e = cb + (size_t)k * CDIM;
    double s = 0.0;
    for (int c = 0; c < CDIM; c += 4) {
      const double d0 = (double)zrow[c]     - (double)e[c];
      const double d1 = (double)zrow[c + 1] - (double)e[c + 1];
      const double d2 = (double)zrow[c + 2] - (double)e[c + 2];
      const double d3 = (double)zrow[c + 3] - (double)e[c + 3];
      s += d0 * d0 + d1 * d1 + d2 * d2 + d3 * d3;
    }
    if (s < best) { best = s; bi = k; }
  }
  svals[tid] = best; sidx[tid] = bi;
  __syncthreads();
  if (tid == 0) {
    double bv = svals[0]; int bx = sidx[0];
    for (int i = 1; i < 256; ++i)
      if (svals[i] < bv || (svals[i] == bv && sidx[i] < bx)) { bv = svals[i]; bx = sidx[i]; }
    idxi[t] = bx;
    idx_f[t] = (float)bx;
  }
}

// ---------------- K3: out = codebook[idx] @ W_out^T + b_out -------------------
__global__ __launch_bounds__(256) void k_proj_out(const float* __restrict__ cb,
                                                  const int* __restrict__ idxi,
                                                  const float* __restrict__ Wout,
                                                  const float* __restrict__ bout,
                                                  float* __restrict__ out) {
  __shared__ float Qs[16][68];
  __shared__ float Ws[16][68];
  __shared__ int sidx[64];
  const int tok0 = blockIdx.x * 64;
  const int d0 = blockIdx.y * 64;
  const int tid = threadIdx.x;
  const int tx = tid & 15, ty = tid >> 4;
  if (tid < 64) sidx[tid] = idxi[tok0 + tid];
  float acc[4][4] = {};
  for (int kb = 0; kb < CDIM; kb += 16) {
    __syncthreads();
    {
      const int r = tid >> 2;
      const int kq = (tid & 3) * 4;
      const float4 q4 = *(const float4*)(cb + (size_t)sidx[r] * CDIM + kb + kq);
      Qs[kq + 0][r] = q4.x; Qs[kq + 1][r] = q4.y; Qs[kq + 2][r] = q4.z; Qs[kq + 3][r] = q4.w;
      const float4 w4 = *(const float4*)(Wout + (size_t)(d0 + r) * CDIM + kb + kq);
      Ws[kq + 0][r] = w4.x; Ws[kq + 1][r] = w4.y; Ws[kq + 2][r] = w4.z; Ws[kq + 3][r] = w4.w;
    }
    __syncthreads();
#pragma unroll
    for (int kk = 0; kk < 16; ++kk) {
      const float4 qv = *(const float4*)&Qs[kk][tx * 4];
#pragma unroll
      for (int i = 0; i < 4; ++i) {
        const float wv = Ws[kk][ty * 4 + i];
        acc[i][0] = fmaf(wv, qv.x, acc[i][0]);
        acc[i][1] = fmaf(wv, qv.y, acc[i][1]);
        acc[i][2] = fmaf(wv, qv.z, acc[i][2]);
        acc[i][3] = fmaf(wv, qv.w, acc[i][3]);
      }
    }
  }
  const int b = tok0 / HW;
  const int n0 = tok0 % HW;
  float* ob = out + (size_t)b * DIN * HW + n0;
#pragma unroll
  for (int i = 0; i < 4; ++i) {
    const int d = d0 + ty * 4 + i;
    const float bb = bout[d];
    float4 o;
    o.x = acc[i][0] + bb; o.y = acc[i][1] + bb;
    o.z = acc[i][2] + bb; o.w = acc[i][3] + bb;
    *(float4*)(ob + (size_t)d * HW + tx * 4) = o;
  }
}

// ---------------- K4: commitment loss = mean((q - z)^2) -----------------------
__global__ __launch_bounds__(256) void k_loss(const short* __restrict__ z_hi,
                                              const short* __restrict__ z_lo,
                                              const float* __restrict__ cb,
                                              const int* __restrict__ idxi,
                                              float* __restrict__ loss) {
  const int wid = (blockIdx.x * blockDim.x + threadIdx.x) >> 6;
  const int lane = threadIdx.x & 63;
  const short4 h4 = *(const short4*)(z_hi + (size_t)wid * CDIM + lane * 4);
  const short4 l4 = *(const short4*)(z_lo + (size_t)wid * CDIM + lane * 4);
  const float4 qv = *(const float4*)(cb + (size_t)idxi[wid] * CDIM + lane * 4);
  const float zx = bf2f(h4.x) + bf2f(l4.x);
  const float zy = bf2f(h4.y) + bf2f(l4.y);
  const float zz = bf2f(h4.z) + bf2f(l4.z);
  const float zw = bf2f(h4.w) + bf2f(l4.w);
  const float dx = qv.x - zx, dy = qv.y - zy, dz2 = qv.z - zz, dw = qv.w - zw;
  float s = dx * dx + dy * dy + dz2 * dz2 + dw * dw;
#pragma unroll
  for (int off = 32; off > 0; off >>= 1) s += __shfl_down(s, off, 64);
  if (lane == 0) atomicAdd(loss, s * (1.0f / ((float)NTOK * (float)CDIM)));
}

extern "C" void kernel_launch(void* const* d_in, const int* in_sizes, int n_in,
                              void* d_out, int out_size, void* d_ws, size_t ws_size,
                              hipStream_t stream) {
  const float* x    = (const float*)d_in[0];
  const float* Win  = (const float*)d_in[1];
  const float* bin  = (const float*)d_in[2];
  const float* Wout = (const float*)d_in[3];
  const float* bout = (const float*)d_in[4];
  const float* cb   = (const float*)d_in[5];

  float* out   = (float*)d_out;
  float* idx_f = out + OUT_ELEMS;
  float* loss  = out + OUT_ELEMS + NTOK;

  char* w = (char*)d_ws;
  size_t off = 0;
  short* z_hi  = (short*)(w + off); off += (size_t)NTOK * CDIM * 2;    // 8 MB
  short* z_lo  = (short*)(w + off); off += (size_t)NTOK * CDIM * 2;    // 8 MB
  short* cb_hi = (short*)(w + off); off += (size_t)KCODES * CDIM * 2;  // 4 MB
  short* cb_lo = (short*)(w + off); off += (size_t)KCODES * CDIM * 2;  // 4 MB
  float* ee    = (float*)(w + off); off += (size_t)KCODES * 4;
  int*   idxi  = (int*)(w + off);   off += (size_t)NTOK * 4;
  int*   flags = (int*)(w + off);   off += (size_t)NTOK * 4;
  float* pmv   = (float*)(w + off); off += (size_t)NPART * NTOK * 4;
  int*   pmi   = (int*)(w + off);   off += (size_t)NPART * NTOK * 4;
  float* psv   = (float*)(w + off); off += (size_t)NPART * NTOK * 4;

  hipMemsetAsync(loss, 0, sizeof(float), stream);

  k_prep_cb    <<<dim3(KCODES / 4),           dim3(256), 0, stream>>>(cb, cb_hi, cb_lo, ee);
  k_proj_in    <<<dim3(NTOK / 64, CDIM / 64), dim3(256), 0, stream>>>(x, Win, bin, z_hi, z_lo);
  k_argmin_mfma<<<dim3(NTOK / 128, NSTRIP),   dim3(256), 0, stream>>>(z_hi, z_lo, cb_hi, cb_lo,
                                                                      ee, pmv, pmi, psv);
  k_merge16    <<<dim3(NTOK / 256),           dim3(256), 0, stream>>>(pmv, pmi, psv, idxi, idx_f, flags);
  k_rescue     <<<dim3(NTOK),                 dim3(256), 0, stream>>>(z_hi, z_lo, cb, flags, idxi, idx_f);
  k_proj_out   <<<dim3(NTOK / 64, DIN / 64),  dim3(256), 0, stream>>>(cb, idxi, Wout, bout, out);
  k_loss       <<<dim3(NTOK / 4),             dim3(256), 0, stream>>>(z_hi, z_lo, cb, idxi, loss);
}

// Round 4
// 726.020 us; speedup vs baseline: 2.6867x; 1.5655x over previous
//
#include <hip/hip_runtime.h>
#include <cfloat>
#include <cstdint>

// VQ-VAE vector quantizer forward. Round 4: parallel rescue
// (compacted flag list + 32-way code-chunked fp64 rescore; was 471us
// single-block-per-token latency kernel at 1.9% occupancy).
#define B_      16
#define DIN     512
#define HW      1024
#define CDIM    256
#define KCODES  8192
#define NTOK    (B_ * HW)            // 16384
#define OUT_ELEMS (B_ * DIN * HW)    // 8388608
#define GAP_EPS 1e-3f
#define NSTRIP  8                    // K-strips across blockIdx.y
#define NPART   (NSTRIP * 2)         // partials per token (x2: wn halves)
#define CPS     (KCODES / NSTRIP)    // 1024 codes per strip
#define MAXR    4096                 // rescue list capacity (~5 expected)
#define RCHUNK  32                   // code chunks per rescued token
#define RBLOCKS 2048                 // fixed rescue grid

typedef __attribute__((ext_vector_type(8))) short bf16x8;
typedef __attribute__((ext_vector_type(4))) float f32x4;

static __device__ __forceinline__ short f2bf(float f) {
  unsigned u = __builtin_bit_cast(unsigned, f);
  u += 0x7FFFu + ((u >> 16) & 1u);           // RNE
  return (short)(u >> 16);
}
static __device__ __forceinline__ float bf2f(short h) {
  unsigned u = ((unsigned)(unsigned short)h) << 16;
  return __builtin_bit_cast(float, u);
}

#define GLL16(gsrc, ldst)                                                      \
  __builtin_amdgcn_global_load_lds(                                            \
      (const __attribute__((address_space(1))) unsigned int*)(gsrc),           \
      (__attribute__((address_space(3))) unsigned int*)(ldst), 16, 0, 0)

// ---------------- K0: codebook -> bf16 hi/lo + row sumsq ----------------------
__global__ __launch_bounds__(256) void k_prep_cb(const float* __restrict__ cb,
                                                 short* __restrict__ cb_hi,
                                                 short* __restrict__ cb_lo,
                                                 float* __restrict__ ee) {
  const int wid = (blockIdx.x * 256 + threadIdx.x) >> 6;   // code row
  const int lane = threadIdx.x & 63;
  const float4 v = *(const float4*)(cb + (size_t)wid * CDIM + lane * 4);
  float s = v.x * v.x + v.y * v.y + v.z * v.z + v.w * v.w;
  short4 h, l;
  h.x = f2bf(v.x); l.x = f2bf(v.x - bf2f(h.x));
  h.y = f2bf(v.y); l.y = f2bf(v.y - bf2f(h.y));
  h.z = f2bf(v.z); l.z = f2bf(v.z - bf2f(h.z));
  h.w = f2bf(v.w); l.w = f2bf(v.w - bf2f(h.w));
  *(short4*)(cb_hi + (size_t)wid * CDIM + lane * 4) = h;
  *(short4*)(cb_lo + (size_t)wid * CDIM + lane * 4) = l;
#pragma unroll
  for (int off = 32; off > 0; off >>= 1) s += __shfl_down(s, off, 64);
  if (lane == 0) ee[wid] = s;
}

// ---------------- K1: z = x^T @ W_in^T + b_in, emit z_hi/z_lo (bf16) ---------
__global__ __launch_bounds__(256) void k_proj_in(const float* __restrict__ x,
                                                 const float* __restrict__ Win,
                                                 const float* __restrict__ bin,
                                                 short* __restrict__ z_hi,
                                                 short* __restrict__ z_lo) {
  __shared__ float As[16][68];
  __shared__ float Ws[16][68];
  const int tok0 = blockIdx.x * 64;
  const int col0 = blockIdx.y * 64;
  const int b = tok0 / HW;
  const int n0 = tok0 % HW;
  const float* xb = x + (size_t)b * DIN * HW + n0;
  const int tid = threadIdx.x;
  const int tx = tid & 15, ty = tid >> 4;
  float acc[4][4] = {};
  for (int kb = 0; kb < DIN; kb += 16) {
    __syncthreads();
    {
      const int tok = tid & 63;
      const int kkb = tid >> 6;
#pragma unroll
      for (int r = 0; r < 4; ++r) {
        const int kk = r * 4 + kkb;
        As[kk][tok] = xb[(size_t)(kb + kk) * HW + tok];
      }
      const int col = tid >> 2;
      const int kq = (tid & 3) * 4;
      const float4 w4 = *(const float4*)(Win + (size_t)(col0 + col) * DIN + kb + kq);
      Ws[kq + 0][col] = w4.x; Ws[kq + 1][col] = w4.y;
      Ws[kq + 2][col] = w4.z; Ws[kq + 3][col] = w4.w;
    }
    __syncthreads();
#pragma unroll
    for (int kk = 0; kk < 16; ++kk) {
      const float4 wv = *(const float4*)&Ws[kk][tx * 4];
#pragma unroll
      for (int i = 0; i < 4; ++i) {
        const float a = As[kk][ty * 4 + i];
        acc[i][0] = fmaf(a, wv.x, acc[i][0]);
        acc[i][1] = fmaf(a, wv.y, acc[i][1]);
        acc[i][2] = fmaf(a, wv.z, acc[i][2]);
        acc[i][3] = fmaf(a, wv.w, acc[i][3]);
      }
    }
  }
  const float4 bias = *(const float4*)(bin + col0 + tx * 4);
#pragma unroll
  for (int i = 0; i < 4; ++i) {
    const int t = tok0 + ty * 4 + i;
    float o[4];
    o[0] = acc[i][0] + bias.x; o[1] = acc[i][1] + bias.y;
    o[2] = acc[i][2] + bias.z; o[3] = acc[i][3] + bias.w;
    short4 h, l;
    h.x = f2bf(o[0]); l.x = f2bf(o[0] - bf2f(h.x));
    h.y = f2bf(o[1]); l.y = f2bf(o[1] - bf2f(h.y));
    h.z = f2bf(o[2]); l.z = f2bf(o[2] - bf2f(h.z));
    h.w = f2bf(o[3]); l.w = f2bf(o[3] - bf2f(h.w));
    *(short4*)(z_hi + (size_t)t * CDIM + col0 + tx * 4) = h;
    *(short4*)(z_lo + (size_t)t * CDIM + col0 + tx * 4) = l;
  }
}

// ---------------- K2: MFMA distance GEMM + argmin (split-bf16, 3 products) ----
__global__ __launch_bounds__(256, 2) void k_argmin_mfma(
    const short* __restrict__ z_hi, const short* __restrict__ z_lo,
    const short* __restrict__ cb_hi, const short* __restrict__ cb_lo,
    const float* __restrict__ ee,
    float* __restrict__ pmv, int* __restrict__ pmi, float* __restrict__ psv) {
  __shared__ short lds_s[4 * 128 * 32];          // 32 KB
  char* ldsc = (char*)lds_s;
  const int tid = threadIdx.x;
  const int w = tid >> 6, lane = tid & 63;
  const int quad = lane >> 4, l16 = lane & 15;
  const int wm = w >> 1, wn = w & 1;
  const int tok0 = blockIdx.x * 128;
  const int cbase = blockIdx.y * CPS;

  const int uA = (w << 6) + lane;
  const int uB = uA + 256;
  const int tA = uA >> 2, pA = uA & 3, qA = pA ^ ((tA >> 1) & 3);
  const int tB = uB >> 2, pB = uB & 3, qB = pB ^ ((tB >> 1) & 3);
  const int offA = tA * CDIM + qA * 8;
  const int offB = tB * CDIM + qB * 8;
  const short* gAh0 = z_hi + (size_t)tok0 * CDIM + offA;
  const short* gAh1 = z_hi + (size_t)tok0 * CDIM + offB;
  const short* gAl0 = z_lo + (size_t)tok0 * CDIM + offA;
  const short* gAl1 = z_lo + (size_t)tok0 * CDIM + offB;

  int aoffs[4], boffs[4];
#pragma unroll
  for (int mi = 0; mi < 4; ++mi) {
    const int t = wm * 64 + mi * 16 + l16;
    const int p = quad ^ ((t >> 1) & 3);
    aoffs[mi] = t * 64 + p * 16;
  }
#pragma unroll
  for (int ni = 0; ni < 4; ++ni) {
    const int t = wn * 64 + ni * 16 + l16;
    const int p = quad ^ ((t >> 1) & 3);
    boffs[ni] = 16384 + t * 64 + p * 16;
  }

  float mv[16], sv[16]; int bidx[16];
#pragma unroll
  for (int j = 0; j < 16; ++j) { mv[j] = FLT_MAX; sv[j] = FLT_MAX; bidx[j] = 0; }

  for (int ct = 0; ct < CPS / 128; ++ct) {
    const int ctile = cbase + ct * 128;
    const short* gBh0 = cb_hi + (size_t)ctile * CDIM + offA;
    const short* gBh1 = cb_hi + (size_t)ctile * CDIM + offB;
    const short* gBl0 = cb_lo + (size_t)ctile * CDIM + offA;
    const short* gBl1 = cb_lo + (size_t)ctile * CDIM + offB;
    f32x4 acc[4][4];
#pragma unroll
    for (int mi = 0; mi < 4; ++mi)
#pragma unroll
      for (int ni = 0; ni < 4; ++ni) acc[mi][ni] = (f32x4){0.f, 0.f, 0.f, 0.f};

    for (int kb = 0; kb < CDIM; kb += 32) {
      __syncthreads();
      GLL16(gAh0 + kb, ldsc + ((0 * 4 + w) << 10));
      GLL16(gAh1 + kb, ldsc + ((1 * 4 + w) << 10));
      GLL16(gAl0 + kb, ldsc + ((2 * 4 + w) << 10));
      GLL16(gAl1 + kb, ldsc + ((3 * 4 + w) << 10));
      GLL16(gBh0 + kb, ldsc + ((4 * 4 + w) << 10));
      GLL16(gBh1 + kb, ldsc + ((5 * 4 + w) << 10));
      GLL16(gBl0 + kb, ldsc + ((6 * 4 + w) << 10));
      GLL16(gBl1 + kb, ldsc + ((7 * 4 + w) << 10));
      __syncthreads();
      bf16x8 ah[4], al[4], bh[4], bl[4];
#pragma unroll
      for (int mi = 0; mi < 4; ++mi) {
        ah[mi] = *(const bf16x8*)(ldsc + aoffs[mi]);
        al[mi] = *(const bf16x8*)(ldsc + 8192 + aoffs[mi]);
      }
#pragma unroll
      for (int ni = 0; ni < 4; ++ni) {
        bh[ni] = *(const bf16x8*)(ldsc + boffs[ni]);
        bl[ni] = *(const bf16x8*)(ldsc + 8192 + boffs[ni]);
      }
#pragma unroll
      for (int mi = 0; mi < 4; ++mi)
#pragma unroll
        for (int ni = 0; ni < 4; ++ni) {
          f32x4 c = acc[mi][ni];
          c = __builtin_amdgcn_mfma_f32_16x16x32_bf16(ah[mi], bh[ni], c, 0, 0, 0);
          c = __builtin_amdgcn_mfma_f32_16x16x32_bf16(ah[mi], bl[ni], c, 0, 0, 0);
          c = __builtin_amdgcn_mfma_f32_16x16x32_bf16(al[mi], bh[ni], c, 0, 0, 0);
          acc[mi][ni] = c;
        }
    }
    float eev[4];
#pragma unroll
    for (int ni = 0; ni < 4; ++ni) eev[ni] = ee[ctile + wn * 64 + ni * 16 + l16];
#pragma unroll
    for (int mi = 0; mi < 4; ++mi)
#pragma unroll
      for (int r = 0; r < 4; ++r) {
        const int j = mi * 4 + r;
#pragma unroll
        for (int ni = 0; ni < 4; ++ni) {
          const float s = fmaf(-2.0f, acc[mi][ni][r], eev[ni]);
          const int code = ctile + wn * 64 + ni * 16 + l16;
          if (s < mv[j]) { sv[j] = mv[j]; mv[j] = s; bidx[j] = code; }
          else if (s < sv[j]) sv[j] = s;
        }
      }
  }
#pragma unroll
  for (int off = 1; off < 16; off <<= 1) {
#pragma unroll
    for (int j = 0; j < 16; ++j) {
      const float ov = __shfl_xor(mv[j], off, 64);
      const int   oi = __shfl_xor(bidx[j], off, 64);
      const float os = __shfl_xor(sv[j], off, 64);
      const float snew = fminf(fminf(sv[j], os), fmaxf(mv[j], ov));
      if (ov < mv[j] || (ov == mv[j] && oi < bidx[j])) { mv[j] = ov; bidx[j] = oi; }
      sv[j] = snew;
    }
  }
  if (l16 == 0) {
    const int strip = blockIdx.y * 2 + wn;
#pragma unroll
    for (int j = 0; j < 16; ++j) {
      const int mi = j >> 2, r = j & 3;
      const int t = tok0 + wm * 64 + mi * 16 + quad * 4 + r;
      const size_t o = (size_t)strip * NTOK + t;
      pmv[o] = mv[j]; pmi[o] = bidx[j]; psv[o] = sv[j];
    }
  }
}

// ---------------- K2b: merge 16 partials, emit indices + compacted rescue list
__global__ __launch_bounds__(256) void k_merge16(const float* __restrict__ pmv,
                                                 const int* __restrict__ pmi,
                                                 const float* __restrict__ psv,
                                                 int* __restrict__ idxi,
                                                 float* __restrict__ idx_f,
                                                 int* __restrict__ rlist,
                                                 int* __restrict__ rcount) {
  const int t = blockIdx.x * 256 + threadIdx.x;
  float mv = FLT_MAX, sv = FLT_MAX; int mi = 0x7fffffff;
#pragma unroll
  for (int s = 0; s < NPART; ++s) {
    const float v = pmv[(size_t)s * NTOK + t];
    const int   i = pmi[(size_t)s * NTOK + t];
    const float s2 = psv[(size_t)s * NTOK + t];
    if (v < mv || (v == mv && i < mi)) { sv = fminf(mv, s2); mv = v; mi = i; }
    else sv = fminf(sv, v);
  }
  idxi[t] = mi;
  idx_f[t] = (float)mi;
  if (sv - mv < GAP_EPS) {
    const int pos = atomicAdd(rcount, 1);
    if (pos < MAXR) rlist[pos] = t;
  }
}

// ---------------- K2c: chunked fp64 rescore (block = token x 256-code chunk) --
__global__ __launch_bounds__(256) void k_rescue_chunk(
    const short* __restrict__ z_hi, const short* __restrict__ z_lo,
    const float* __restrict__ cb,
    const int* __restrict__ rlist, const int* __restrict__ rcount,
    double* __restrict__ slotv, int* __restrict__ sloti) {
  const int cnt0 = *rcount;
  const int cnt = cnt0 < MAXR ? cnt0 : MAXR;
  const int li0 = blockIdx.x >> 5;               // token-list index
  const int chunk = blockIdx.x & (RCHUNK - 1);   // code chunk
  if (li0 >= cnt) return;
  __shared__ float zrow[CDIM];
  __shared__ double rv[256];
  __shared__ int ri[256];
  const int tid = threadIdx.x;
  for (int li = li0; li < cnt; li += RBLOCKS / RCHUNK) {
    const int t = rlist[li];
    zrow[tid] = bf2f(z_hi[(size_t)t * CDIM + tid]) + bf2f(z_lo[(size_t)t * CDIM + tid]);
    __syncthreads();
    const int k = chunk * 256 + tid;             // one code per thread
    const float* e = cb + (size_t)k * CDIM;
    double s0 = 0.0, s1 = 0.0, s2 = 0.0, s3 = 0.0;
    for (int c = 0; c < CDIM; c += 4) {
      const double d0 = (double)zrow[c]     - (double)e[c];
      const double d1 = (double)zrow[c + 1] - (double)e[c + 1];
      const double d2 = (double)zrow[c + 2] - (double)e[c + 2];
      const double d3 = (double)zrow[c + 3] - (double)e[c + 3];
      s0 += d0 * d0; s1 += d1 * d1; s2 += d2 * d2; s3 += d3 * d3;
    }
    rv[tid] = (s0 + s1) + (s2 + s3);
    ri[tid] = k;
    __syncthreads();
    for (int off = 128; off > 0; off >>= 1) {
      if (tid < off) {
        if (rv[tid + off] < rv[tid] ||
            (rv[tid + off] == rv[tid] && ri[tid + off] < ri[tid])) {
          rv[tid] = rv[tid + off]; ri[tid] = ri[tid + off];
        }
      }
      __syncthreads();
    }
    if (tid == 0) {
      slotv[(size_t)li * RCHUNK + chunk] = rv[0];
      sloti[(size_t)li * RCHUNK + chunk] = ri[0];
    }
    __syncthreads();                             // zrow reuse guard
  }
}

// ---------------- K2d: fold chunk slots, patch indices ------------------------
__global__ __launch_bounds__(256) void k_rescue_fin(
    const double* __restrict__ slotv, const int* __restrict__ sloti,
    const int* __restrict__ rlist, const int* __restrict__ rcount,
    int* __restrict__ idxi, float* __restrict__ idx_f) {
  const int cnt0 = *rcount;
  const int cnt = cnt0 < MAXR ? cnt0 : MAXR;
  for (int li = threadIdx.x; li < cnt; li += 256) {
    double bv = slotv[(size_t)li * RCHUNK];
    int bx = sloti[(size_t)li * RCHUNK];
    for (int c = 1; c < RCHUNK; ++c) {
      const double v = slotv[(size_t)li * RCHUNK + c];
      const int i = sloti[(size_t)li * RCHUNK + c];
      if (v < bv || (v == bv && i < bx)) { bv = v; bx = i; }
    }
    const int t = rlist[li];
    idxi[t] = bx;
    idx_f[t] = (float)bx;
  }
}

// ---------------- K3: out = codebook[idx] @ W_out^T + b_out -------------------
__global__ __launch_bounds__(256) void k_proj_out(const float* __restrict__ cb,
                                                  const int* __restrict__ idxi,
                                                  const float* __restrict__ Wout,
                                                  const float* __restrict__ bout,
                                                  float* __restrict__ out) {
  __shared__ float Qs[16][68];
  __shared__ float Ws[16][68];
  __shared__ int sidx[64];
  const int tok0 = blockIdx.x * 64;
  const int d0 = blockIdx.y * 64;
  const int tid = threadIdx.x;
  const int tx = tid & 15, ty = tid >> 4;
  if (tid < 64) sidx[tid] = idxi[tok0 + tid];
  float acc[4][4] = {};
  for (int kb = 0; kb < CDIM; kb += 16) {
    __syncthreads();
    {
      const int r = tid >> 2;
      const int kq = (tid & 3) * 4;
      const float4 q4 = *(const float4*)(cb + (size_t)sidx[r] * CDIM + kb + kq);
      Qs[kq + 0][r] = q4.x; Qs[kq + 1][r] = q4.y; Qs[kq + 2][r] = q4.z; Qs[kq + 3][r] = q4.w;
      const float4 w4 = *(const float4*)(Wout + (size_t)(d0 + r) * CDIM + kb + kq);
      Ws[kq + 0][r] = w4.x; Ws[kq + 1][r] = w4.y; Ws[kq + 2][r] = w4.z; Ws[kq + 3][r] = w4.w;
    }
    __syncthreads();
#pragma unroll
    for (int kk = 0; kk < 16; ++kk) {
      const float4 qv = *(const float4*)&Qs[kk][tx * 4];
#pragma unroll
      for (int i = 0; i < 4; ++i) {
        const float wv = Ws[kk][ty * 4 + i];
        acc[i][0] = fmaf(wv, qv.x, acc[i][0]);
        acc[i][1] = fmaf(wv, qv.y, acc[i][1]);
        acc[i][2] = fmaf(wv, qv.z, acc[i][2]);
        acc[i][3] = fmaf(wv, qv.w, acc[i][3]);
      }
    }
  }
  const int b = tok0 / HW;
  const int n0 = tok0 % HW;
  float* ob = out + (size_t)b * DIN * HW + n0;
#pragma unroll
  for (int i = 0; i < 4; ++i) {
    const int d = d0 + ty * 4 + i;
    const float bb = bout[d];
    float4 o;
    o.x = acc[i][0] + bb; o.y = acc[i][1] + bb;
    o.z = acc[i][2] + bb; o.w = acc[i][3] + bb;
    *(float4*)(ob + (size_t)d * HW + tx * 4) = o;
  }
}

// ---------------- K4: commitment loss = mean((q - z)^2) -----------------------
__global__ __launch_bounds__(256) void k_loss(const short* __restrict__ z_hi,
                                              const short* __restrict__ z_lo,
                                              const float* __restrict__ cb,
                                              const int* __restrict__ idxi,
                                              float* __restrict__ loss) {
  const int wid = (blockIdx.x * blockDim.x + threadIdx.x) >> 6;
  const int lane = threadIdx.x & 63;
  const short4 h4 = *(const short4*)(z_hi + (size_t)wid * CDIM + lane * 4);
  const short4 l4 = *(const short4*)(z_lo + (size_t)wid * CDIM + lane * 4);
  const float4 qv = *(const float4*)(cb + (size_t)idxi[wid] * CDIM + lane * 4);
  const float zx = bf2f(h4.x) + bf2f(l4.x);
  const float zy = bf2f(h4.y) + bf2f(l4.y);
  const float zz = bf2f(h4.z) + bf2f(l4.z);
  const float zw = bf2f(h4.w) + bf2f(l4.w);
  const float dx = qv.x - zx, dy = qv.y - zy, dz2 = qv.z - zz, dw = qv.w - zw;
  float s = dx * dx + dy * dy + dz2 * dz2 + dw * dw;
#pragma unroll
  for (int off = 32; off > 0; off >>= 1) s += __shfl_down(s, off, 64);
  if (lane == 0) atomicAdd(loss, s * (1.0f / ((float)NTOK * (float)CDIM)));
}

extern "C" void kernel_launch(void* const* d_in, const int* in_sizes, int n_in,
                              void* d_out, int out_size, void* d_ws, size_t ws_size,
                              hipStream_t stream) {
  const float* x    = (const float*)d_in[0];
  const float* Win  = (const float*)d_in[1];
  const float* bin  = (const float*)d_in[2];
  const float* Wout = (const float*)d_in[3];
  const float* bout = (const float*)d_in[4];
  const float* cb   = (const float*)d_in[5];

  float* out   = (float*)d_out;
  float* idx_f = out + OUT_ELEMS;
  float* loss  = out + OUT_ELEMS + NTOK;

  char* w = (char*)d_ws;
  size_t off = 0;
  short* z_hi  = (short*)(w + off); off += (size_t)NTOK * CDIM * 2;    // 8 MB
  short* z_lo  = (short*)(w + off); off += (size_t)NTOK * CDIM * 2;    // 8 MB
  short* cb_hi = (short*)(w + off); off += (size_t)KCODES * CDIM * 2;  // 4 MB
  short* cb_lo = (short*)(w + off); off += (size_t)KCODES * CDIM * 2;  // 4 MB
  float* ee    = (float*)(w + off); off += (size_t)KCODES * 4;
  int*   idxi  = (int*)(w + off);   off += (size_t)NTOK * 4;
  float* pmv   = (float*)(w + off); off += (size_t)NPART * NTOK * 4;
  int*   pmi   = (int*)(w + off);   off += (size_t)NPART * NTOK * 4;
  float* psv   = (float*)(w + off); off += (size_t)NPART * NTOK * 4;
  int*   rlist = (int*)(w + off);   off += (size_t)MAXR * 4;
  int*   rcount= (int*)(w + off);   off += 256;                        // padded
  double* slotv= (double*)(w + off);off += (size_t)MAXR * RCHUNK * 8;  // 1 MB
  int*   sloti = (int*)(w + off);   off += (size_t)MAXR * RCHUNK * 4;  // 0.5 MB

  hipMemsetAsync(loss, 0, sizeof(float), stream);
  hipMemsetAsync(rcount, 0, sizeof(int), stream);

  k_prep_cb    <<<dim3(KCODES / 4),           dim3(256), 0, stream>>>(cb, cb_hi, cb_lo, ee);
  k_proj_in    <<<dim3(NTOK / 64, CDIM / 64), dim3(256), 0, stream>>>(x, Win, bin, z_hi, z_lo);
  k_argmin_mfma<<<dim3(NTOK / 128, NSTRIP),   dim3(256), 0, stream>>>(z_hi, z_lo, cb_hi, cb_lo,
                                                                      ee, pmv, pmi, psv);
  k_merge16    <<<dim3(NTOK / 256),           dim3(256), 0, stream>>>(pmv, pmi, psv, idxi, idx_f,
                                                                      rlist, rcount);
  k_rescue_chunk<<<dim3(RBLOCKS),             dim3(256), 0, stream>>>(z_hi, z_lo, cb, rlist, rcount,
                                                                      slotv, sloti);
  k_rescue_fin <<<dim3(1),                    dim3(256), 0, stream>>>(slotv, sloti, rlist, rcount,
                                                                      idxi, idx_f);
  k_proj_out   <<<dim3(NTOK / 64, DIN / 64),  dim3(256), 0, stream>>>(cb, idxi, Wout, bout, out);
  k_loss       <<<dim3(NTOK / 4),             dim3(256), 0, stream>>>(z_hi, z_lo, cb, idxi, loss);
}

// Round 5
// 672.291 us; speedup vs baseline: 2.9014x; 1.0799x over previous
//
#include <hip/hip_runtime.h>
#include <cfloat>
#include <cstdint>

// VQ-VAE vector quantizer forward. Round 5: both projections moved onto the
// validated split-bf16 MFMA GEMM skeleton (x pre-transposed; proj_out computed
// transposed with gathered-codebook B so C-cols = contiguous hw).
#define B_      16
#define DIN     512
#define HW      1024
#define CDIM    256
#define KCODES  8192
#define NTOK    (B_ * HW)            // 16384
#define OUT_ELEMS (B_ * DIN * HW)    // 8388608
#define GAP_EPS 1e-3f
#define NSTRIP  8
#define NPART   (NSTRIP * 2)
#define CPS     (KCODES / NSTRIP)    // 1024
#define MAXR    4096
#define RCHUNK  32
#define RBLOCKS 2048

typedef __attribute__((ext_vector_type(8))) short bf16x8;
typedef __attribute__((ext_vector_type(4))) float f32x4;

static __device__ __forceinline__ short f2bf(float f) {
  unsigned u = __builtin_bit_cast(unsigned, f);
  u += 0x7FFFu + ((u >> 16) & 1u);           // RNE
  return (short)(u >> 16);
}
static __device__ __forceinline__ float bf2f(short h) {
  unsigned u = ((unsigned)(unsigned short)h) << 16;
  return __builtin_bit_cast(float, u);
}

#define GLL16(gsrc, ldst)                                                      \
  __builtin_amdgcn_global_load_lds(                                            \
      (const __attribute__((address_space(1))) unsigned int*)(gsrc),           \
      (__attribute__((address_space(3))) unsigned int*)(ldst), 16, 0, 0)

// ---------------- K0a: codebook -> bf16 hi/lo + row sumsq ---------------------
__global__ __launch_bounds__(256) void k_prep_cb(const float* __restrict__ cb,
                                                 short* __restrict__ cb_hi,
                                                 short* __restrict__ cb_lo,
                                                 float* __restrict__ ee) {
  const int wid = (blockIdx.x * 256 + threadIdx.x) >> 6;
  const int lane = threadIdx.x & 63;
  const float4 v = *(const float4*)(cb + (size_t)wid * CDIM + lane * 4);
  float s = v.x * v.x + v.y * v.y + v.z * v.z + v.w * v.w;
  short4 h, l;
  h.x = f2bf(v.x); l.x = f2bf(v.x - bf2f(h.x));
  h.y = f2bf(v.y); l.y = f2bf(v.y - bf2f(h.y));
  h.z = f2bf(v.z); l.z = f2bf(v.z - bf2f(h.z));
  h.w = f2bf(v.w); l.w = f2bf(v.w - bf2f(h.w));
  *(short4*)(cb_hi + (size_t)wid * CDIM + lane * 4) = h;
  *(short4*)(cb_lo + (size_t)wid * CDIM + lane * 4) = l;
#pragma unroll
  for (int off = 32; off > 0; off >>= 1) s += __shfl_down(s, off, 64);
  if (lane == 0) ee[wid] = s;
}

// ---------------- K0b: W_in / W_out -> bf16 hi/lo -----------------------------
__global__ __launch_bounds__(256) void k_prep_w(const float* __restrict__ Win,
                                                const float* __restrict__ Wout,
                                                short* __restrict__ wi_hi,
                                                short* __restrict__ wi_lo,
                                                short* __restrict__ wo_hi,
                                                short* __restrict__ wo_lo) {
  const int i = (blockIdx.x * 256 + threadIdx.x) * 4;   // 131072 elems each
  {
    const float4 v = *(const float4*)(Win + i);
    short4 h, l;
    h.x = f2bf(v.x); l.x = f2bf(v.x - bf2f(h.x));
    h.y = f2bf(v.y); l.y = f2bf(v.y - bf2f(h.y));
    h.z = f2bf(v.z); l.z = f2bf(v.z - bf2f(h.z));
    h.w = f2bf(v.w); l.w = f2bf(v.w - bf2f(h.w));
    *(short4*)(wi_hi + i) = h; *(short4*)(wi_lo + i) = l;
  }
  {
    const float4 v = *(const float4*)(Wout + i);
    short4 h, l;
    h.x = f2bf(v.x); l.x = f2bf(v.x - bf2f(h.x));
    h.y = f2bf(v.y); l.y = f2bf(v.y - bf2f(h.y));
    h.z = f2bf(v.z); l.z = f2bf(v.z - bf2f(h.z));
    h.w = f2bf(v.w); l.w = f2bf(v.w - bf2f(h.w));
    *(short4*)(wo_hi + i) = h; *(short4*)(wo_lo + i) = l;
  }
}

// ---------------- K0c: transpose x[b,d,hw] -> xT[tok][din] bf16 hi/lo ---------
__global__ __launch_bounds__(256) void k_prep_x(const float* __restrict__ x,
                                                short* __restrict__ xT_hi,
                                                short* __restrict__ xT_lo) {
  __shared__ float T[64][65];
  const int b = blockIdx.x >> 4;
  const int hw0 = (blockIdx.x & 15) * 64;
  const int din0 = blockIdx.y * 64;
  const int tid = threadIdx.x;
  {
    const int r = tid >> 2;                 // din row in tile
    const int c = tid & 3;                  // 16-wide hw group
    const float* src = x + ((size_t)b * DIN + din0 + r) * HW + hw0 + c * 16;
#pragma unroll
    for (int j = 0; j < 4; ++j) {
      const float4 v = *(const float4*)(src + j * 4);
      T[r][c * 16 + j * 4 + 0] = v.x;
      T[r][c * 16 + j * 4 + 1] = v.y;
      T[r][c * 16 + j * 4 + 2] = v.z;
      T[r][c * 16 + j * 4 + 3] = v.w;
    }
  }
  __syncthreads();
  {
    const int tt = tid & 63;                // token in tile
    const int c2 = tid >> 6;                // 16-wide din group
    short h[16], l[16];
#pragma unroll
    for (int j = 0; j < 16; ++j) {
      const float f = T[c2 * 16 + j][tt];
      h[j] = f2bf(f); l[j] = f2bf(f - bf2f(h[j]));
    }
    const size_t base = ((size_t)b * HW + hw0 + tt) * DIN + din0 + c2 * 16;
    *(bf16x8*)(xT_hi + base)     = *(bf16x8*)&h[0];
    *(bf16x8*)(xT_hi + base + 8) = *(bf16x8*)&h[8];
    *(bf16x8*)(xT_lo + base)     = *(bf16x8*)&l[0];
    *(bf16x8*)(xT_lo + base + 8) = *(bf16x8*)&l[8];
  }
}

// ---------------- K1: proj_in MFMA: z = xT @ Win^T + b_in ---------------------
// 128 tok x 128 cd tile, K=512 (BK=32). Same staging/swizzle as argmin.
__global__ __launch_bounds__(256, 2) void k_proj_in_mfma(
    const short* __restrict__ xT_hi, const short* __restrict__ xT_lo,
    const short* __restrict__ wi_hi, const short* __restrict__ wi_lo,
    const float* __restrict__ bin,
    short* __restrict__ z_hi, short* __restrict__ z_lo) {
  __shared__ short lds_s[4 * 128 * 32];
  char* ldsc = (char*)lds_s;
  const int tid = threadIdx.x;
  const int w = tid >> 6, lane = tid & 63;
  const int quad = lane >> 4, l16 = lane & 15;
  const int wm = w >> 1, wn = w & 1;
  const int tok0 = blockIdx.x * 128;
  const int cd0 = blockIdx.y * 128;

  const int uA = (w << 6) + lane, uB = uA + 256;
  const int tA = uA >> 2, pA = uA & 3, qA = pA ^ ((tA >> 1) & 3);
  const int tB = uB >> 2, pB = uB & 3, qB = pB ^ ((tB >> 1) & 3);
  const int offA = tA * DIN + qA * 8;       // stride = DIN for both A and B
  const int offB = tB * DIN + qB * 8;
  const short* gAh0 = xT_hi + (size_t)tok0 * DIN + offA;
  const short* gAh1 = xT_hi + (size_t)tok0 * DIN + offB;
  const short* gAl0 = xT_lo + (size_t)tok0 * DIN + offA;
  const short* gAl1 = xT_lo + (size_t)tok0 * DIN + offB;
  const short* gBh0 = wi_hi + (size_t)cd0 * DIN + offA;
  const short* gBh1 = wi_hi + (size_t)cd0 * DIN + offB;
  const short* gBl0 = wi_lo + (size_t)cd0 * DIN + offA;
  const short* gBl1 = wi_lo + (size_t)cd0 * DIN + offB;

  int aoffs[4], boffs[4];
#pragma unroll
  for (int mi = 0; mi < 4; ++mi) {
    const int t = wm * 64 + mi * 16 + l16;
    aoffs[mi] = t * 64 + (quad ^ ((t >> 1) & 3)) * 16;
  }
#pragma unroll
  for (int ni = 0; ni < 4; ++ni) {
    const int t = wn * 64 + ni * 16 + l16;
    boffs[ni] = 16384 + t * 64 + (quad ^ ((t >> 1) & 3)) * 16;
  }

  f32x4 acc[4][4];
#pragma unroll
  for (int mi = 0; mi < 4; ++mi)
#pragma unroll
    for (int ni = 0; ni < 4; ++ni) acc[mi][ni] = (f32x4){0.f, 0.f, 0.f, 0.f};

  for (int kb = 0; kb < DIN; kb += 32) {
    __syncthreads();
    GLL16(gAh0 + kb, ldsc + ((0 * 4 + w) << 10));
    GLL16(gAh1 + kb, ldsc + ((1 * 4 + w) << 10));
    GLL16(gAl0 + kb, ldsc + ((2 * 4 + w) << 10));
    GLL16(gAl1 + kb, ldsc + ((3 * 4 + w) << 10));
    GLL16(gBh0 + kb, ldsc + ((4 * 4 + w) << 10));
    GLL16(gBh1 + kb, ldsc + ((5 * 4 + w) << 10));
    GLL16(gBl0 + kb, ldsc + ((6 * 4 + w) << 10));
    GLL16(gBl1 + kb, ldsc + ((7 * 4 + w) << 10));
    __syncthreads();
    bf16x8 ah[4], al[4], bh[4], bl[4];
#pragma unroll
    for (int mi = 0; mi < 4; ++mi) {
      ah[mi] = *(const bf16x8*)(ldsc + aoffs[mi]);
      al[mi] = *(const bf16x8*)(ldsc + 8192 + aoffs[mi]);
    }
#pragma unroll
    for (int ni = 0; ni < 4; ++ni) {
      bh[ni] = *(const bf16x8*)(ldsc + boffs[ni]);
      bl[ni] = *(const bf16x8*)(ldsc + 8192 + boffs[ni]);
    }
#pragma unroll
    for (int mi = 0; mi < 4; ++mi)
#pragma unroll
      for (int ni = 0; ni < 4; ++ni) {
        f32x4 c = acc[mi][ni];
        c = __builtin_amdgcn_mfma_f32_16x16x32_bf16(ah[mi], bh[ni], c, 0, 0, 0);
        c = __builtin_amdgcn_mfma_f32_16x16x32_bf16(ah[mi], bl[ni], c, 0, 0, 0);
        c = __builtin_amdgcn_mfma_f32_16x16x32_bf16(al[mi], bh[ni], c, 0, 0, 0);
        acc[mi][ni] = c;
      }
  }
  // epilogue: bias + split-bf16 store; C layout col=l16 (cd), row=quad*4+r (tok)
  float bv[4];
#pragma unroll
  for (int ni = 0; ni < 4; ++ni) bv[ni] = bin[cd0 + wn * 64 + ni * 16 + l16];
#pragma unroll
  for (int mi = 0; mi < 4; ++mi)
#pragma unroll
    for (int r = 0; r < 4; ++r) {
      const int t = tok0 + wm * 64 + mi * 16 + quad * 4 + r;
#pragma unroll
      for (int ni = 0; ni < 4; ++ni) {
        const int cd = cd0 + wn * 64 + ni * 16 + l16;
        const float o = acc[mi][ni][r] + bv[ni];
        const short h = f2bf(o);
        z_hi[(size_t)t * CDIM + cd] = h;
        z_lo[(size_t)t * CDIM + cd] = f2bf(o - bf2f(h));
      }
    }
}

// ---------------- K2: MFMA distance GEMM + argmin (unchanged) -----------------
__global__ __launch_bounds__(256, 2) void k_argmin_mfma(
    const short* __restrict__ z_hi, const short* __restrict__ z_lo,
    const short* __restrict__ cb_hi, const short* __restrict__ cb_lo,
    const float* __restrict__ ee,
    float* __restrict__ pmv, int* __restrict__ pmi, float* __restrict__ psv) {
  __shared__ short lds_s[4 * 128 * 32];
  char* ldsc = (char*)lds_s;
  const int tid = threadIdx.x;
  const int w = tid >> 6, lane = tid & 63;
  const int quad = lane >> 4, l16 = lane & 15;
  const int wm = w >> 1, wn = w & 1;
  const int tok0 = blockIdx.x * 128;
  const int cbase = blockIdx.y * CPS;

  const int uA = (w << 6) + lane, uB = uA + 256;
  const int tA = uA >> 2, pA = uA & 3, qA = pA ^ ((tA >> 1) & 3);
  const int tB = uB >> 2, pB = uB & 3, qB = pB ^ ((tB >> 1) & 3);
  const int offA = tA * CDIM + qA * 8;
  const int offB = tB * CDIM + qB * 8;
  const short* gAh0 = z_hi + (size_t)tok0 * CDIM + offA;
  const short* gAh1 = z_hi + (size_t)tok0 * CDIM + offB;
  const short* gAl0 = z_lo + (size_t)tok0 * CDIM + offA;
  const short* gAl1 = z_lo + (size_t)tok0 * CDIM + offB;

  int aoffs[4], boffs[4];
#pragma unroll
  for (int mi = 0; mi < 4; ++mi) {
    const int t = wm * 64 + mi * 16 + l16;
    aoffs[mi] = t * 64 + (quad ^ ((t >> 1) & 3)) * 16;
  }
#pragma unroll
  for (int ni = 0; ni < 4; ++ni) {
    const int t = wn * 64 + ni * 16 + l16;
    boffs[ni] = 16384 + t * 64 + (quad ^ ((t >> 1) & 3)) * 16;
  }

  float mv[16], sv[16]; int bidx[16];
#pragma unroll
  for (int j = 0; j < 16; ++j) { mv[j] = FLT_MAX; sv[j] = FLT_MAX; bidx[j] = 0; }

  for (int ct = 0; ct < CPS / 128; ++ct) {
    const int ctile = cbase + ct * 128;
    const short* gBh0 = cb_hi + (size_t)ctile * CDIM + offA;
    const short* gBh1 = cb_hi + (size_t)ctile * CDIM + offB;
    const short* gBl0 = cb_lo + (size_t)ctile * CDIM + offA;
    const short* gBl1 = cb_lo + (size_t)ctile * CDIM + offB;
    f32x4 acc[4][4];
#pragma unroll
    for (int mi = 0; mi < 4; ++mi)
#pragma unroll
      for (int ni = 0; ni < 4; ++ni) acc[mi][ni] = (f32x4){0.f, 0.f, 0.f, 0.f};

    for (int kb = 0; kb < CDIM; kb += 32) {
      __syncthreads();
      GLL16(gAh0 + kb, ldsc + ((0 * 4 + w) << 10));
      GLL16(gAh1 + kb, ldsc + ((1 * 4 + w) << 10));
      GLL16(gAl0 + kb, ldsc + ((2 * 4 + w) << 10));
      GLL16(gAl1 + kb, ldsc + ((3 * 4 + w) << 10));
      GLL16(gBh0 + kb, ldsc + ((4 * 4 + w) << 10));
      GLL16(gBh1 + kb, ldsc + ((5 * 4 + w) << 10));
      GLL16(gBl0 + kb, ldsc + ((6 * 4 + w) << 10));
      GLL16(gBl1 + kb, ldsc + ((7 * 4 + w) << 10));
      __syncthreads();
      bf16x8 ah[4], al[4], bh[4], bl[4];
#pragma unroll
      for (int mi = 0; mi < 4; ++mi) {
        ah[mi] = *(const bf16x8*)(ldsc + aoffs[mi]);
        al[mi] = *(const bf16x8*)(ldsc + 8192 + aoffs[mi]);
      }
#pragma unroll
      for (int ni = 0; ni < 4; ++ni) {
        bh[ni] = *(const bf16x8*)(ldsc + boffs[ni]);
        bl[ni] = *(const bf16x8*)(ldsc + 8192 + boffs[ni]);
      }
#pragma unroll
      for (int mi = 0; mi < 4; ++mi)
#pragma unroll
        for (int ni = 0; ni < 4; ++ni) {
          f32x4 c = acc[mi][ni];
          c = __builtin_amdgcn_mfma_f32_16x16x32_bf16(ah[mi], bh[ni], c, 0, 0, 0);
          c = __builtin_amdgcn_mfma_f32_16x16x32_bf16(ah[mi], bl[ni], c, 0, 0, 0);
          c = __builtin_amdgcn_mfma_f32_16x16x32_bf16(al[mi], bh[ni], c, 0, 0, 0);
          acc[mi][ni] = c;
        }
    }
    float eev[4];
#pragma unroll
    for (int ni = 0; ni < 4; ++ni) eev[ni] = ee[ctile + wn * 64 + ni * 16 + l16];
#pragma unroll
    for (int mi = 0; mi < 4; ++mi)
#pragma unroll
      for (int r = 0; r < 4; ++r) {
        const int j = mi * 4 + r;
#pragma unroll
        for (int ni = 0; ni < 4; ++ni) {
          const float s = fmaf(-2.0f, acc[mi][ni][r], eev[ni]);
          const int code = ctile + wn * 64 + ni * 16 + l16;
          if (s < mv[j]) { sv[j] = mv[j]; mv[j] = s; bidx[j] = code; }
          else if (s < sv[j]) sv[j] = s;
        }
      }
  }
#pragma unroll
  for (int off = 1; off < 16; off <<= 1) {
#pragma unroll
    for (int j = 0; j < 16; ++j) {
      const float ov = __shfl_xor(mv[j], off, 64);
      const int   oi = __shfl_xor(bidx[j], off, 64);
      const float os = __shfl_xor(sv[j], off, 64);
      const float snew = fminf(fminf(sv[j], os), fmaxf(mv[j], ov));
      if (ov < mv[j] || (ov == mv[j] && oi < bidx[j])) { mv[j] = ov; bidx[j] = oi; }
      sv[j] = snew;
    }
  }
  if (l16 == 0) {
    const int strip = blockIdx.y * 2 + wn;
#pragma unroll
    for (int j = 0; j < 16; ++j) {
      const int mi = j >> 2, r = j & 3;
      const int t = tok0 + wm * 64 + mi * 16 + quad * 4 + r;
      const size_t o = (size_t)strip * NTOK + t;
      pmv[o] = mv[j]; pmi[o] = bidx[j]; psv[o] = sv[j];
    }
  }
}

// ---------------- K2b: merge 16 partials + compacted rescue list --------------
__global__ __launch_bounds__(256) void k_merge16(const float* __restrict__ pmv,
                                                 const int* __restrict__ pmi,
                                                 const float* __restrict__ psv,
                                                 int* __restrict__ idxi,
                                                 float* __restrict__ idx_f,
                                                 int* __restrict__ rlist,
                                                 int* __restrict__ rcount) {
  const int t = blockIdx.x * 256 + threadIdx.x;
  float mv = FLT_MAX, sv = FLT_MAX; int mi = 0x7fffffff;
#pragma unroll
  for (int s = 0; s < NPART; ++s) {
    const float v = pmv[(size_t)s * NTOK + t];
    const int   i = pmi[(size_t)s * NTOK + t];
    const float s2 = psv[(size_t)s * NTOK + t];
    if (v < mv || (v == mv && i < mi)) { sv = fminf(mv, s2); mv = v; mi = i; }
    else sv = fminf(sv, v);
  }
  idxi[t] = mi;
  idx_f[t] = (float)mi;
  if (sv - mv < GAP_EPS) {
    const int pos = atomicAdd(rcount, 1);
    if (pos < MAXR) rlist[pos] = t;
  }
}

// ---------------- K2c: chunked fp64 rescore -----------------------------------
__global__ __launch_bounds__(256) void k_rescue_chunk(
    const short* __restrict__ z_hi, const short* __restrict__ z_lo,
    const float* __restrict__ cb,
    const int* __restrict__ rlist, const int* __restrict__ rcount,
    double* __restrict__ slotv, int* __restrict__ sloti) {
  const int cnt0 = *rcount;
  const int cnt = cnt0 < MAXR ? cnt0 : MAXR;
  const int li0 = blockIdx.x >> 5;
  const int chunk = blockIdx.x & (RCHUNK - 1);
  if (li0 >= cnt) return;
  __shared__ float zrow[CDIM];
  __shared__ double rv[256];
  __shared__ int ri[256];
  const int tid = threadIdx.x;
  for (int li = li0; li < cnt; li += RBLOCKS / RCHUNK) {
    const int t = rlist[li];
    zrow[tid] = bf2f(z_hi[(size_t)t * CDIM + tid]) + bf2f(z_lo[(size_t)t * CDIM + tid]);
    __syncthreads();
    const int k = chunk * 256 + tid;
    const float* e = cb + (size_t)k * CDIM;
    double s0 = 0.0, s1 = 0.0, s2 = 0.0, s3 = 0.0;
    for (int c = 0; c < CDIM; c += 4) {
      const double d0 = (double)zrow[c]     - (double)e[c];
      const double d1 = (double)zrow[c + 1] - (double)e[c + 1];
      const double d2 = (double)zrow[c + 2] - (double)e[c + 2];
      const double d3 = (double)zrow[c + 3] - (double)e[c + 3];
      s0 += d0 * d0; s1 += d1 * d1; s2 += d2 * d2; s3 += d3 * d3;
    }
    rv[tid] = (s0 + s1) + (s2 + s3);
    ri[tid] = k;
    __syncthreads();
    for (int off = 128; off > 0; off >>= 1) {
      if (tid < off) {
        if (rv[tid + off] < rv[tid] ||
            (rv[tid + off] == rv[tid] && ri[tid + off] < ri[tid])) {
          rv[tid] = rv[tid + off]; ri[tid] = ri[tid + off];
        }
      }
      __syncthreads();
    }
    if (tid == 0) {
      slotv[(size_t)li * RCHUNK + chunk] = rv[0];
      sloti[(size_t)li * RCHUNK + chunk] = ri[0];
    }
    __syncthreads();
  }
}

// ---------------- K2d: fold chunk slots, patch indices ------------------------
__global__ __launch_bounds__(256) void k_rescue_fin(
    const double* __restrict__ slotv, const int* __restrict__ sloti,
    const int* __restrict__ rlist, const int* __restrict__ rcount,
    int* __restrict__ idxi, float* __restrict__ idx_f) {
  const int cnt0 = *rcount;
  const int cnt = cnt0 < MAXR ? cnt0 : MAXR;
  for (int li = threadIdx.x; li < cnt; li += 256) {
    double bv = slotv[(size_t)li * RCHUNK];
    int bx = sloti[(size_t)li * RCHUNK];
    for (int c = 1; c < RCHUNK; ++c) {
      const double v = slotv[(size_t)li * RCHUNK + c];
      const int i = sloti[(size_t)li * RCHUNK + c];
      if (v < bv || (v == bv && i < bx)) { bv = v; bx = i; }
    }
    const int t = rlist[li];
    idxi[t] = bx;
    idx_f[t] = (float)bx;
  }
}

// ---------------- K3: proj_out MFMA (transposed): out[din][tok] --------------
// A = W_out rows (din, k=cd), B = gathered cb_hi/lo[idx[tok]] rows (tok, k=cd).
// C col=l16 -> contiguous hw for coalesced stores into out[b,din,hw].
__global__ __launch_bounds__(256, 2) void k_proj_out_mfma(
    const short* __restrict__ wo_hi, const short* __restrict__ wo_lo,
    const short* __restrict__ cb_hi, const short* __restrict__ cb_lo,
    const int* __restrict__ idxi, const float* __restrict__ bout,
    float* __restrict__ out) {
  __shared__ short lds_s[4 * 128 * 32];
  char* ldsc = (char*)lds_s;
  const int tid = threadIdx.x;
  const int w = tid >> 6, lane = tid & 63;
  const int quad = lane >> 4, l16 = lane & 15;
  const int wm = w >> 1, wn = w & 1;
  const int tok0 = blockIdx.x * 128;
  const int din0 = blockIdx.y * 128;

  const int uA = (w << 6) + lane, uB = uA + 256;
  const int tA = uA >> 2, pA = uA & 3, qA = pA ^ ((tA >> 1) & 3);
  const int tB = uB >> 2, pB = uB & 3, qB = pB ^ ((tB >> 1) & 3);
  // A = W_out rows din0+t (stride CDIM)
  const short* gAh0 = wo_hi + (size_t)(din0 + tA) * CDIM + qA * 8;
  const short* gAh1 = wo_hi + (size_t)(din0 + tB) * CDIM + qB * 8;
  const short* gAl0 = wo_lo + (size_t)(din0 + tA) * CDIM + qA * 8;
  const short* gAl1 = wo_lo + (size_t)(din0 + tB) * CDIM + qB * 8;
  // B = codebook rows gathered via idx (per-lane source address)
  const int iA = idxi[tok0 + tA];
  const int iB = idxi[tok0 + tB];
  const short* gBh0 = cb_hi + (size_t)iA * CDIM + qA * 8;
  const short* gBh1 = cb_hi + (size_t)iB * CDIM + qB * 8;
  const short* gBl0 = cb_lo + (size_t)iA * CDIM + qA * 8;
  const short* gBl1 = cb_lo + (size_t)iB * CDIM + qB * 8;

  int aoffs[4], boffs[4];
#pragma unroll
  for (int mi = 0; mi < 4; ++mi) {
    const int t = wm * 64 + mi * 16 + l16;
    aoffs[mi] = t * 64 + (quad ^ ((t >> 1) & 3)) * 16;
  }
#pragma unroll
  for (int ni = 0; ni < 4; ++ni) {
    const int t = wn * 64 + ni * 16 + l16;
    boffs[ni] = 16384 + t * 64 + (quad ^ ((t >> 1) & 3)) * 16;
  }

  f32x4 acc[4][4];
#pragma unroll
  for (int mi = 0; mi < 4; ++mi)
#pragma unroll
    for (int ni = 0; ni < 4; ++ni) acc[mi][ni] = (f32x4){0.f, 0.f, 0.f, 0.f};

  for (int kb = 0; kb < CDIM; kb += 32) {
    __syncthreads();
    GLL16(gAh0 + kb, ldsc + ((0 * 4 + w) << 10));
    GLL16(gAh1 + kb, ldsc + ((1 * 4 + w) << 10));
    GLL16(gAl0 + kb, ldsc + ((2 * 4 + w) << 10));
    GLL16(gAl1 + kb, ldsc + ((3 * 4 + w) << 10));
    GLL16(gBh0 + kb, ldsc + ((4 * 4 + w) << 10));
    GLL16(gBh1 + kb, ldsc + ((5 * 4 + w) << 10));
    GLL16(gBl0 + kb, ldsc + ((6 * 4 + w) << 10));
    GLL16(gBl1 + kb, ldsc + ((7 * 4 + w) << 10));
    __syncthreads();
    bf16x8 ah[4], al[4], bh[4], bl[4];
#pragma unroll
    for (int mi = 0; mi < 4; ++mi) {
      ah[mi] = *(const bf16x8*)(ldsc + aoffs[mi]);
      al[mi] = *(const bf16x8*)(ldsc + 8192 + aoffs[mi]);
    }
#pragma unroll
    for (int ni = 0; ni < 4; ++ni) {
      bh[ni] = *(const bf16x8*)(ldsc + boffs[ni]);
      bl[ni] = *(const bf16x8*)(ldsc + 8192 + boffs[ni]);
    }
#pragma unroll
    for (int mi = 0; mi < 4; ++mi)
#pragma unroll
      for (int ni = 0; ni < 4; ++ni) {
        f32x4 c = acc[mi][ni];
        c = __builtin_amdgcn_mfma_f32_16x16x32_bf16(ah[mi], bh[ni], c, 0, 0, 0);
        c = __builtin_amdgcn_mfma_f32_16x16x32_bf16(ah[mi], bl[ni], c, 0, 0, 0);
        c = __builtin_amdgcn_mfma_f32_16x16x32_bf16(al[mi], bh[ni], c, 0, 0, 0);
        acc[mi][ni] = c;
      }
  }
  // epilogue: out[b][din][hw]; row=quad*4+r -> din, col=l16 -> tok (contig hw)
  const int b = tok0 >> 10;
  const int hwb = tok0 & (HW - 1);
  float* ob = out + (size_t)b * DIN * HW;
#pragma unroll
  for (int mi = 0; mi < 4; ++mi)
#pragma unroll
    for (int r = 0; r < 4; ++r) {
      const int din = din0 + wm * 64 + mi * 16 + quad * 4 + r;
      const float bb = bout[din];
#pragma unroll
      for (int ni = 0; ni < 4; ++ni) {
        const int hw = hwb + wn * 64 + ni * 16 + l16;
        ob[(size_t)din * HW + hw] = acc[mi][ni][r] + bb;
      }
    }
}

// ---------------- K4: commitment loss = mean((q - z)^2) -----------------------
__global__ __launch_bounds__(256) void k_loss(const short* __restrict__ z_hi,
                                              const short* __restrict__ z_lo,
                                              const float* __restrict__ cb,
                                              const int* __restrict__ idxi,
                                              float* __restrict__ loss) {
  const int wid = (blockIdx.x * blockDim.x + threadIdx.x) >> 6;
  const int lane = threadIdx.x & 63;
  const short4 h4 = *(const short4*)(z_hi + (size_t)wid * CDIM + lane * 4);
  const short4 l4 = *(const short4*)(z_lo + (size_t)wid * CDIM + lane * 4);
  const float4 qv = *(const float4*)(cb + (size_t)idxi[wid] * CDIM + lane * 4);
  const float zx = bf2f(h4.x) + bf2f(l4.x);
  const float zy = bf2f(h4.y) + bf2f(l4.y);
  const float zz = bf2f(h4.z) + bf2f(l4.z);
  const float zw = bf2f(h4.w) + bf2f(l4.w);
  const float dx = qv.x - zx, dy = qv.y - zy, dz2 = qv.z - zz, dw = qv.w - zw;
  float s = dx * dx + dy * dy + dz2 * dz2 + dw * dw;
#pragma unroll
  for (int off = 32; off > 0; off >>= 1) s += __shfl_down(s, off, 64);
  if (lane == 0) atomicAdd(loss, s * (1.0f / ((float)NTOK * (float)CDIM)));
}

extern "C" void kernel_launch(void* const* d_in, const int* in_sizes, int n_in,
                              void* d_out, int out_size, void* d_ws, size_t ws_size,
                              hipStream_t stream) {
  const float* x    = (const float*)d_in[0];
  const float* Win  = (const float*)d_in[1];
  const float* bin  = (const float*)d_in[2];
  const float* Wout = (const float*)d_in[3];
  const float* bout = (const float*)d_in[4];
  const float* cb   = (const float*)d_in[5];

  float* out   = (float*)d_out;
  float* idx_f = out + OUT_ELEMS;
  float* loss  = out + OUT_ELEMS + NTOK;

  char* w = (char*)d_ws;
  size_t off = 0;
  short* z_hi  = (short*)(w + off); off += (size_t)NTOK * CDIM * 2;    // 8 MB
  short* z_lo  = (short*)(w + off); off += (size_t)NTOK * CDIM * 2;    // 8 MB
  short* cb_hi = (short*)(w + off); off += (size_t)KCODES * CDIM * 2;  // 4 MB
  short* cb_lo = (short*)(w + off); off += (size_t)KCODES * CDIM * 2;  // 4 MB
  short* xT_hi = (short*)(w + off); off += (size_t)NTOK * DIN * 2;     // 16 MB
  short* xT_lo = (short*)(w + off); off += (size_t)NTOK * DIN * 2;     // 16 MB
  short* wi_hi = (short*)(w + off); off += (size_t)CDIM * DIN * 2;     // 256 KB
  short* wi_lo = (short*)(w + off); off += (size_t)CDIM * DIN * 2;
  short* wo_hi = (short*)(w + off); off += (size_t)DIN * CDIM * 2;
  short* wo_lo = (short*)(w + off); off += (size_t)DIN * CDIM * 2;
  float* ee    = (float*)(w + off); off += (size_t)KCODES * 4;
  int*   idxi  = (int*)(w + off);   off += (size_t)NTOK * 4;
  float* pmv   = (float*)(w + off); off += (size_t)NPART * NTOK * 4;
  int*   pmi   = (int*)(w + off);   off += (size_t)NPART * NTOK * 4;
  float* psv   = (float*)(w + off); off += (size_t)NPART * NTOK * 4;
  int*   rlist = (int*)(w + off);   off += (size_t)MAXR * 4;
  int*   rcount= (int*)(w + off);   off += 256;
  double* slotv= (double*)(w + off);off += (size_t)MAXR * RCHUNK * 8;
  int*   sloti = (int*)(w + off);   off += (size_t)MAXR * RCHUNK * 4;

  hipMemsetAsync(loss, 0, sizeof(float), stream);
  hipMemsetAsync(rcount, 0, sizeof(int), stream);

  k_prep_cb     <<<dim3(KCODES / 4),            dim3(256), 0, stream>>>(cb, cb_hi, cb_lo, ee);
  k_prep_w      <<<dim3(128),                   dim3(256), 0, stream>>>(Win, Wout, wi_hi, wi_lo,
                                                                        wo_hi, wo_lo);
  k_prep_x      <<<dim3(16 * B_, DIN / 64),     dim3(256), 0, stream>>>(x, xT_hi, xT_lo);
  k_proj_in_mfma<<<dim3(NTOK / 128, CDIM / 128), dim3(256), 0, stream>>>(xT_hi, xT_lo, wi_hi, wi_lo,
                                                                         bin, z_hi, z_lo);
  k_argmin_mfma <<<dim3(NTOK / 128, NSTRIP),    dim3(256), 0, stream>>>(z_hi, z_lo, cb_hi, cb_lo,
                                                                        ee, pmv, pmi, psv);
  k_merge16     <<<dim3(NTOK / 256),            dim3(256), 0, stream>>>(pmv, pmi, psv, idxi, idx_f,
                                                                        rlist, rcount);
  k_rescue_chunk<<<dim3(RBLOCKS),               dim3(256), 0, stream>>>(z_hi, z_lo, cb, rlist, rcount,
                                                                        slotv, sloti);
  k_rescue_fin  <<<dim3(1),                     dim3(256), 0, stream>>>(slotv, sloti, rlist, rcount,
                                                                        idxi, idx_f);
  k_proj_out_mfma<<<dim3(NTOK / 128, DIN / 128), dim3(256), 0, stream>>>(wo_hi, wo_lo, cb_hi, cb_lo,
                                                                         idxi, bout, out);
  k_loss        <<<dim3(NTOK / 4),              dim3(256), 0, stream>>>(z_hi, z_lo, cb, idxi, loss);
}

// Round 6
// 461.350 us; speedup vs baseline: 4.2280x; 1.4572x over previous
//
#include <hip/hip_runtime.h>
#include <cfloat>
#include <cstdint>

// VQ-VAE vector quantizer forward. Round 6: dispatch fusion (13 -> 7),
// loss folded into merge (block-reduced atomics), rescue_fin patches loss,
// argmin epilogue min/max formulation.
#define B_      16
#define DIN     512
#define HW      1024
#define CDIM    256
#define KCODES  8192
#define NTOK    (B_ * HW)            // 16384
#define OUT_ELEMS (B_ * DIN * HW)    // 8388608
#define GAP_EPS 1e-3f
#define NSTRIP  8
#define NPART   (NSTRIP * 2)
#define CPS     (KCODES / NSTRIP)    // 1024
#define MAXR    4096
#define RCHUNK  32
#define RBLOCKS 2048
#define LOSS_SCALE (1.0f / ((float)NTOK * (float)CDIM))

typedef __attribute__((ext_vector_type(8))) short bf16x8;
typedef __attribute__((ext_vector_type(4))) float f32x4;

static __device__ __forceinline__ short f2bf(float f) {
  unsigned u = __builtin_bit_cast(unsigned, f);
  u += 0x7FFFu + ((u >> 16) & 1u);           // RNE
  return (short)(u >> 16);
}
static __device__ __forceinline__ float bf2f(short h) {
  unsigned u = ((unsigned)(unsigned short)h) << 16;
  return __builtin_bit_cast(float, u);
}

#define GLL16(gsrc, ldst)                                                      \
  __builtin_amdgcn_global_load_lds(                                            \
      (const __attribute__((address_space(1))) unsigned int*)(gsrc),           \
      (__attribute__((address_space(3))) unsigned int*)(ldst), 16, 0, 0)

// ---------------- K0: fused prep: cb hi/lo + ee | W hi/lo | xT hi/lo ---------
// grid regions: [0,2048) cb, [2048,2176) weights, [2176,4224) x-transpose.
#define PREP_CB_BLKS 2048
#define PREP_W_BLKS  128
#define PREP_X_BLKS  2048
__global__ __launch_bounds__(256) void k_prep(
    const float* __restrict__ cb, const float* __restrict__ Win,
    const float* __restrict__ Wout, const float* __restrict__ x,
    short* __restrict__ cb_hi, short* __restrict__ cb_lo, float* __restrict__ ee,
    short* __restrict__ wi_hi, short* __restrict__ wi_lo,
    short* __restrict__ wo_hi, short* __restrict__ wo_lo,
    short* __restrict__ xT_hi, short* __restrict__ xT_lo,
    float* __restrict__ loss, int* __restrict__ rcount) {
  __shared__ float T[64][65];
  const int blk = blockIdx.x;
  const int tid = threadIdx.x;
  if (blk == 0 && tid < 2) {
    if (tid == 0) *loss = 0.0f; else *rcount = 0;
  }
  if (blk < PREP_CB_BLKS) {
    const int wid = (blk * 256 + tid) >> 6;
    const int lane = tid & 63;
    const float4 v = *(const float4*)(cb + (size_t)wid * CDIM + lane * 4);
    float s = v.x * v.x + v.y * v.y + v.z * v.z + v.w * v.w;
    short4 h, l;
    h.x = f2bf(v.x); l.x = f2bf(v.x - bf2f(h.x));
    h.y = f2bf(v.y); l.y = f2bf(v.y - bf2f(h.y));
    h.z = f2bf(v.z); l.z = f2bf(v.z - bf2f(h.z));
    h.w = f2bf(v.w); l.w = f2bf(v.w - bf2f(h.w));
    *(short4*)(cb_hi + (size_t)wid * CDIM + lane * 4) = h;
    *(short4*)(cb_lo + (size_t)wid * CDIM + lane * 4) = l;
#pragma unroll
    for (int off = 32; off > 0; off >>= 1) s += __shfl_down(s, off, 64);
    if (lane == 0) ee[wid] = s;
  } else if (blk < PREP_CB_BLKS + PREP_W_BLKS) {
    const int i = ((blk - PREP_CB_BLKS) * 256 + tid) * 4;
    {
      const float4 v = *(const float4*)(Win + i);
      short4 h, l;
      h.x = f2bf(v.x); l.x = f2bf(v.x - bf2f(h.x));
      h.y = f2bf(v.y); l.y = f2bf(v.y - bf2f(h.y));
      h.z = f2bf(v.z); l.z = f2bf(v.z - bf2f(h.z));
      h.w = f2bf(v.w); l.w = f2bf(v.w - bf2f(h.w));
      *(short4*)(wi_hi + i) = h; *(short4*)(wi_lo + i) = l;
    }
    {
      const float4 v = *(const float4*)(Wout + i);
      short4 h, l;
      h.x = f2bf(v.x); l.x = f2bf(v.x - bf2f(h.x));
      h.y = f2bf(v.y); l.y = f2bf(v.y - bf2f(h.y));
      h.z = f2bf(v.z); l.z = f2bf(v.z - bf2f(h.z));
      h.w = f2bf(v.w); l.w = f2bf(v.w - bf2f(h.w));
      *(short4*)(wo_hi + i) = h; *(short4*)(wo_lo + i) = l;
    }
  } else {
    const int id = blk - PREP_CB_BLKS - PREP_W_BLKS;
    const int xb = id & 255, yb = id >> 8;
    const int b = xb >> 4;
    const int hw0 = (xb & 15) * 64;
    const int din0 = yb * 64;
    {
      const int r = tid >> 2;
      const int c = tid & 3;
      const float* src = x + ((size_t)b * DIN + din0 + r) * HW + hw0 + c * 16;
#pragma unroll
      for (int j = 0; j < 4; ++j) {
        const float4 v = *(const float4*)(src + j * 4);
        T[r][c * 16 + j * 4 + 0] = v.x;
        T[r][c * 16 + j * 4 + 1] = v.y;
        T[r][c * 16 + j * 4 + 2] = v.z;
        T[r][c * 16 + j * 4 + 3] = v.w;
      }
    }
    __syncthreads();
    {
      const int tt = tid & 63;
      const int c2 = tid >> 6;
      short h[16], l[16];
#pragma unroll
      for (int j = 0; j < 16; ++j) {
        const float f = T[c2 * 16 + j][tt];
        h[j] = f2bf(f); l[j] = f2bf(f - bf2f(h[j]));
      }
      const size_t base = ((size_t)b * HW + hw0 + tt) * DIN + din0 + c2 * 16;
      *(bf16x8*)(xT_hi + base)     = *(bf16x8*)&h[0];
      *(bf16x8*)(xT_hi + base + 8) = *(bf16x8*)&h[8];
      *(bf16x8*)(xT_lo + base)     = *(bf16x8*)&l[0];
      *(bf16x8*)(xT_lo + base + 8) = *(bf16x8*)&l[8];
    }
  }
}

// ---------------- K1: proj_in MFMA: z = xT @ Win^T + b_in ---------------------
__global__ __launch_bounds__(256, 2) void k_proj_in_mfma(
    const short* __restrict__ xT_hi, const short* __restrict__ xT_lo,
    const short* __restrict__ wi_hi, const short* __restrict__ wi_lo,
    const float* __restrict__ bin,
    short* __restrict__ z_hi, short* __restrict__ z_lo) {
  __shared__ short lds_s[4 * 128 * 32];
  char* ldsc = (char*)lds_s;
  const int tid = threadIdx.x;
  const int w = tid >> 6, lane = tid & 63;
  const int quad = lane >> 4, l16 = lane & 15;
  const int wm = w >> 1, wn = w & 1;
  const int tok0 = blockIdx.x * 128;
  const int cd0 = blockIdx.y * 128;

  const int uA = (w << 6) + lane, uB = uA + 256;
  const int tA = uA >> 2, pA = uA & 3, qA = pA ^ ((tA >> 1) & 3);
  const int tB = uB >> 2, pB = uB & 3, qB = pB ^ ((tB >> 1) & 3);
  const int offA = tA * DIN + qA * 8;
  const int offB = tB * DIN + qB * 8;
  const short* gAh0 = xT_hi + (size_t)tok0 * DIN + offA;
  const short* gAh1 = xT_hi + (size_t)tok0 * DIN + offB;
  const short* gAl0 = xT_lo + (size_t)tok0 * DIN + offA;
  const short* gAl1 = xT_lo + (size_t)tok0 * DIN + offB;
  const short* gBh0 = wi_hi + (size_t)cd0 * DIN + offA;
  const short* gBh1 = wi_hi + (size_t)cd0 * DIN + offB;
  const short* gBl0 = wi_lo + (size_t)cd0 * DIN + offA;
  const short* gBl1 = wi_lo + (size_t)cd0 * DIN + offB;

  int aoffs[4], boffs[4];
#pragma unroll
  for (int mi = 0; mi < 4; ++mi) {
    const int t = wm * 64 + mi * 16 + l16;
    aoffs[mi] = t * 64 + (quad ^ ((t >> 1) & 3)) * 16;
  }
#pragma unroll
  for (int ni = 0; ni < 4; ++ni) {
    const int t = wn * 64 + ni * 16 + l16;
    boffs[ni] = 16384 + t * 64 + (quad ^ ((t >> 1) & 3)) * 16;
  }

  f32x4 acc[4][4];
#pragma unroll
  for (int mi = 0; mi < 4; ++mi)
#pragma unroll
    for (int ni = 0; ni < 4; ++ni) acc[mi][ni] = (f32x4){0.f, 0.f, 0.f, 0.f};

  for (int kb = 0; kb < DIN; kb += 32) {
    __syncthreads();
    GLL16(gAh0 + kb, ldsc + ((0 * 4 + w) << 10));
    GLL16(gAh1 + kb, ldsc + ((1 * 4 + w) << 10));
    GLL16(gAl0 + kb, ldsc + ((2 * 4 + w) << 10));
    GLL16(gAl1 + kb, ldsc + ((3 * 4 + w) << 10));
    GLL16(gBh0 + kb, ldsc + ((4 * 4 + w) << 10));
    GLL16(gBh1 + kb, ldsc + ((5 * 4 + w) << 10));
    GLL16(gBl0 + kb, ldsc + ((6 * 4 + w) << 10));
    GLL16(gBl1 + kb, ldsc + ((7 * 4 + w) << 10));
    __syncthreads();
    bf16x8 ah[4], al[4], bh[4], bl[4];
#pragma unroll
    for (int mi = 0; mi < 4; ++mi) {
      ah[mi] = *(const bf16x8*)(ldsc + aoffs[mi]);
      al[mi] = *(const bf16x8*)(ldsc + 8192 + aoffs[mi]);
    }
#pragma unroll
    for (int ni = 0; ni < 4; ++ni) {
      bh[ni] = *(const bf16x8*)(ldsc + boffs[ni]);
      bl[ni] = *(const bf16x8*)(ldsc + 8192 + boffs[ni]);
    }
#pragma unroll
    for (int mi = 0; mi < 4; ++mi)
#pragma unroll
      for (int ni = 0; ni < 4; ++ni) {
        f32x4 c = acc[mi][ni];
        c = __builtin_amdgcn_mfma_f32_16x16x32_bf16(ah[mi], bh[ni], c, 0, 0, 0);
        c = __builtin_amdgcn_mfma_f32_16x16x32_bf16(ah[mi], bl[ni], c, 0, 0, 0);
        c = __builtin_amdgcn_mfma_f32_16x16x32_bf16(al[mi], bh[ni], c, 0, 0, 0);
        acc[mi][ni] = c;
      }
  }
  float bv[4];
#pragma unroll
  for (int ni = 0; ni < 4; ++ni) bv[ni] = bin[cd0 + wn * 64 + ni * 16 + l16];
#pragma unroll
  for (int mi = 0; mi < 4; ++mi)
#pragma unroll
    for (int r = 0; r < 4; ++r) {
      const int t = tok0 + wm * 64 + mi * 16 + quad * 4 + r;
#pragma unroll
      for (int ni = 0; ni < 4; ++ni) {
        const int cd = cd0 + wn * 64 + ni * 16 + l16;
        const float o = acc[mi][ni][r] + bv[ni];
        const short h = f2bf(o);
        z_hi[(size_t)t * CDIM + cd] = h;
        z_lo[(size_t)t * CDIM + cd] = f2bf(o - bf2f(h));
      }
    }
}

// ---------------- K2: MFMA distance GEMM + argmin -----------------------------
__global__ __launch_bounds__(256, 2) void k_argmin_mfma(
    const short* __restrict__ z_hi, const short* __restrict__ z_lo,
    const short* __restrict__ cb_hi, const short* __restrict__ cb_lo,
    const float* __restrict__ ee,
    float* __restrict__ pmv, int* __restrict__ pmi, float* __restrict__ psv) {
  __shared__ short lds_s[4 * 128 * 32];
  char* ldsc = (char*)lds_s;
  const int tid = threadIdx.x;
  const int w = tid >> 6, lane = tid & 63;
  const int quad = lane >> 4, l16 = lane & 15;
  const int wm = w >> 1, wn = w & 1;
  const int tok0 = blockIdx.x * 128;
  const int cbase = blockIdx.y * CPS;

  const int uA = (w << 6) + lane, uB = uA + 256;
  const int tA = uA >> 2, pA = uA & 3, qA = pA ^ ((tA >> 1) & 3);
  const int tB = uB >> 2, pB = uB & 3, qB = pB ^ ((tB >> 1) & 3);
  const int offA = tA * CDIM + qA * 8;
  const int offB = tB * CDIM + qB * 8;
  const short* gAh0 = z_hi + (size_t)tok0 * CDIM + offA;
  const short* gAh1 = z_hi + (size_t)tok0 * CDIM + offB;
  const short* gAl0 = z_lo + (size_t)tok0 * CDIM + offA;
  const short* gAl1 = z_lo + (size_t)tok0 * CDIM + offB;

  int aoffs[4], boffs[4];
#pragma unroll
  for (int mi = 0; mi < 4; ++mi) {
    const int t = wm * 64 + mi * 16 + l16;
    aoffs[mi] = t * 64 + (quad ^ ((t >> 1) & 3)) * 16;
  }
#pragma unroll
  for (int ni = 0; ni < 4; ++ni) {
    const int t = wn * 64 + ni * 16 + l16;
    boffs[ni] = 16384 + t * 64 + (quad ^ ((t >> 1) & 3)) * 16;
  }

  float mv[16], sv[16]; int bidx[16];
#pragma unroll
  for (int j = 0; j < 16; ++j) { mv[j] = FLT_MAX; sv[j] = FLT_MAX; bidx[j] = 0; }

  for (int ct = 0; ct < CPS / 128; ++ct) {
    const int ctile = cbase + ct * 128;
    const short* gBh0 = cb_hi + (size_t)ctile * CDIM + offA;
    const short* gBh1 = cb_hi + (size_t)ctile * CDIM + offB;
    const short* gBl0 = cb_lo + (size_t)ctile * CDIM + offA;
    const short* gBl1 = cb_lo + (size_t)ctile * CDIM + offB;
    f32x4 acc[4][4];
#pragma unroll
    for (int mi = 0; mi < 4; ++mi)
#pragma unroll
      for (int ni = 0; ni < 4; ++ni) acc[mi][ni] = (f32x4){0.f, 0.f, 0.f, 0.f};

    for (int kb = 0; kb < CDIM; kb += 32) {
      __syncthreads();
      GLL16(gAh0 + kb, ldsc + ((0 * 4 + w) << 10));
      GLL16(gAh1 + kb, ldsc + ((1 * 4 + w) << 10));
      GLL16(gAl0 + kb, ldsc + ((2 * 4 + w) << 10));
      GLL16(gAl1 + kb, ldsc + ((3 * 4 + w) << 10));
      GLL16(gBh0 + kb, ldsc + ((4 * 4 + w) << 10));
      GLL16(gBh1 + kb, ldsc + ((5 * 4 + w) << 10));
      GLL16(gBl0 + kb, ldsc + ((6 * 4 + w) << 10));
      GLL16(gBl1 + kb, ldsc + ((7 * 4 + w) << 10));
      __syncthreads();
      bf16x8 ah[4], al[4], bh[4], bl[4];
#pragma unroll
      for (int mi = 0; mi < 4; ++mi) {
        ah[mi] = *(const bf16x8*)(ldsc + aoffs[mi]);
        al[mi] = *(const bf16x8*)(ldsc + 8192 + aoffs[mi]);
      }
#pragma unroll
      for (int ni = 0; ni < 4; ++ni) {
        bh[ni] = *(const bf16x8*)(ldsc + boffs[ni]);
        bl[ni] = *(const bf16x8*)(ldsc + 8192 + boffs[ni]);
      }
#pragma unroll
      for (int mi = 0; mi < 4; ++mi)
#pragma unroll
        for (int ni = 0; ni < 4; ++ni) {
          f32x4 c = acc[mi][ni];
          c = __builtin_amdgcn_mfma_f32_16x16x32_bf16(ah[mi], bh[ni], c, 0, 0, 0);
          c = __builtin_amdgcn_mfma_f32_16x16x32_bf16(ah[mi], bl[ni], c, 0, 0, 0);
          c = __builtin_amdgcn_mfma_f32_16x16x32_bf16(al[mi], bh[ni], c, 0, 0, 0);
          acc[mi][ni] = c;
        }
    }
    float eev[4];
#pragma unroll
    for (int ni = 0; ni < 4; ++ni) eev[ni] = ee[ctile + wn * 64 + ni * 16 + l16];
    const int cb2 = ctile + wn * 64 + l16;
#pragma unroll
    for (int mi = 0; mi < 4; ++mi)
#pragma unroll
      for (int r = 0; r < 4; ++r) {
        const int j = mi * 4 + r;
#pragma unroll
        for (int ni = 0; ni < 4; ++ni) {
          const float s = fmaf(-2.0f, acc[mi][ni][r], eev[ni]);
          // 5-op update: 2nd-best via min/max, best via predicated move
          sv[j] = fminf(sv[j], fmaxf(mv[j], s));
          if (s < mv[j]) { mv[j] = s; bidx[j] = cb2 + ni * 16; }
        }
      }
  }
#pragma unroll
  for (int off = 1; off < 16; off <<= 1) {
#pragma unroll
    for (int j = 0; j < 16; ++j) {
      const float ov = __shfl_xor(mv[j], off, 64);
      const int   oi = __shfl_xor(bidx[j], off, 64);
      const float os = __shfl_xor(sv[j], off, 64);
      const float snew = fminf(fminf(sv[j], os), fmaxf(mv[j], ov));
      if (ov < mv[j] || (ov == mv[j] && oi < bidx[j])) { mv[j] = ov; bidx[j] = oi; }
      sv[j] = snew;
    }
  }
  if (l16 == 0) {
    const int strip = blockIdx.y * 2 + wn;
#pragma unroll
    for (int j = 0; j < 16; ++j) {
      const int mi = j >> 2, r = j & 3;
      const int t = tok0 + wm * 64 + mi * 16 + quad * 4 + r;
      const size_t o = (size_t)strip * NTOK + t;
      pmv[o] = mv[j]; pmi[o] = bidx[j]; psv[o] = sv[j];
    }
  }
}

// ---------------- K2b: merge 16 partials + provisional loss (fused) -----------
// one wave per token: lanes 0-15 merge partials; all 64 lanes then compute the
// token's loss contribution with the provisional index; per-block LDS reduce
// -> 1 atomicAdd per block (4096 total). rescue_fin patches rescued tokens.
__global__ __launch_bounds__(256) void k_merge_loss(
    const float* __restrict__ pmv, const int* __restrict__ pmi,
    const float* __restrict__ psv,
    const short* __restrict__ z_hi, const short* __restrict__ z_lo,
    const float* __restrict__ cb,
    int* __restrict__ idxi, float* __restrict__ idx_f,
    int* __restrict__ rlist, int* __restrict__ rcount,
    float* __restrict__ loss) {
  __shared__ float lpart[4];
  const int tid = threadIdx.x;
  const int wv = tid >> 6, lane = tid & 63;
  const int t = blockIdx.x * 4 + wv;
  float mv = FLT_MAX, sv = FLT_MAX; int mi = 0x7fffffff;
  if (lane < NPART) {
    mv = pmv[(size_t)lane * NTOK + t];
    mi = pmi[(size_t)lane * NTOK + t];
    sv = psv[(size_t)lane * NTOK + t];
  }
#pragma unroll
  for (int off = 1; off < 16; off <<= 1) {
    const float ov = __shfl_xor(mv, off, 64);
    const int   oi = __shfl_xor(mi, off, 64);
    const float os = __shfl_xor(sv, off, 64);
    const float snew = fminf(fminf(sv, os), fmaxf(mv, ov));
    if (ov < mv || (ov == mv && oi < mi)) { mv = ov; mi = oi; }
    sv = snew;
  }
  const int mif = __shfl(mi, 0, 64);
  // loss partial: 4 dims per lane
  const short4 h4 = *(const short4*)(z_hi + (size_t)t * CDIM + lane * 4);
  const short4 l4 = *(const short4*)(z_lo + (size_t)t * CDIM + lane * 4);
  const float4 qv = *(const float4*)(cb + (size_t)mif * CDIM + lane * 4);
  const float dx = qv.x - (bf2f(h4.x) + bf2f(l4.x));
  const float dy = qv.y - (bf2f(h4.y) + bf2f(l4.y));
  const float dz = qv.z - (bf2f(h4.z) + bf2f(l4.z));
  const float dw = qv.w - (bf2f(h4.w) + bf2f(l4.w));
  float s = dx * dx + dy * dy + dz * dz + dw * dw;
#pragma unroll
  for (int off = 32; off > 0; off >>= 1) s += __shfl_down(s, off, 64);
  if (lane == 0) {
    idxi[t] = mif;
    idx_f[t] = (float)mif;
    lpart[wv] = s;
    if (sv - mv < GAP_EPS) {
      const int pos = atomicAdd(rcount, 1);
      if (pos < MAXR) rlist[pos] = t;
    }
  }
  __syncthreads();
  if (tid == 0) {
    atomicAdd(loss, (lpart[0] + lpart[1] + lpart[2] + lpart[3]) * LOSS_SCALE);
  }
}

// ---------------- K2c: chunked fp64 rescore -----------------------------------
__global__ __launch_bounds__(256) void k_rescue_chunk(
    const short* __restrict__ z_hi, const short* __restrict__ z_lo,
    const float* __restrict__ cb,
    const int* __restrict__ rlist, const int* __restrict__ rcount,
    double* __restrict__ slotv, int* __restrict__ sloti) {
  const int cnt0 = *rcount;
  const int cnt = cnt0 < MAXR ? cnt0 : MAXR;
  const int li0 = blockIdx.x >> 5;
  const int chunk = blockIdx.x & (RCHUNK - 1);
  if (li0 >= cnt) return;
  __shared__ float zrow[CDIM];
  __shared__ double rv[256];
  __shared__ int ri[256];
  const int tid = threadIdx.x;
  for (int li = li0; li < cnt; li += RBLOCKS / RCHUNK) {
    const int t = rlist[li];
    zrow[tid] = bf2f(z_hi[(size_t)t * CDIM + tid]) + bf2f(z_lo[(size_t)t * CDIM + tid]);
    __syncthreads();
    const int k = chunk * 256 + tid;
    const float* e = cb + (size_t)k * CDIM;
    double s0 = 0.0, s1 = 0.0, s2 = 0.0, s3 = 0.0;
    for (int c = 0; c < CDIM; c += 4) {
      const double d0 = (double)zrow[c]     - (double)e[c];
      const double d1 = (double)zrow[c + 1] - (double)e[c + 1];
      const double d2 = (double)zrow[c + 2] - (double)e[c + 2];
      const double d3 = (double)zrow[c + 3] - (double)e[c + 3];
      s0 += d0 * d0; s1 += d1 * d1; s2 += d2 * d2; s3 += d3 * d3;
    }
    rv[tid] = (s0 + s1) + (s2 + s3);
    ri[tid] = k;
    __syncthreads();
    for (int off = 128; off > 0; off >>= 1) {
      if (tid < off) {
        if (rv[tid + off] < rv[tid] ||
            (rv[tid + off] == rv[tid] && ri[tid + off] < ri[tid])) {
          rv[tid] = rv[tid + off]; ri[tid] = ri[tid + off];
        }
      }
      __syncthreads();
    }
    if (tid == 0) {
      slotv[(size_t)li * RCHUNK + chunk] = rv[0];
      sloti[(size_t)li * RCHUNK + chunk] = ri[0];
    }
    __syncthreads();
  }
}

// ---------------- K2d: fold chunk slots, patch indices + loss delta -----------
__global__ __launch_bounds__(256) void k_rescue_fin(
    const double* __restrict__ slotv, const int* __restrict__ sloti,
    const int* __restrict__ rlist, const int* __restrict__ rcount,
    const short* __restrict__ z_hi, const short* __restrict__ z_lo,
    const float* __restrict__ cb,
    int* __restrict__ idxi, float* __restrict__ idx_f, float* __restrict__ loss) {
  const int cnt0 = *rcount;
  const int cnt = cnt0 < MAXR ? cnt0 : MAXR;
  const int tid = threadIdx.x;
  const int wv = tid >> 6, lane = tid & 63;
  for (int li = wv; li < cnt; li += 4) {
    double bv = 1e300; int bx = 0x7fffffff;
    if (lane < RCHUNK) {
      bv = slotv[(size_t)li * RCHUNK + lane];
      bx = sloti[(size_t)li * RCHUNK + lane];
    }
#pragma unroll
    for (int off = 1; off < 32; off <<= 1) {
      const double ov = __shfl_xor(bv, off, 64);
      const int   oi = __shfl_xor(bx, off, 64);
      if (ov < bv || (ov == bv && oi < bx)) { bv = ov; bx = oi; }
    }
    const int newi = __shfl(bx, 0, 64);
    const int t = rlist[li];
    const int oldi = idxi[t];
    if (newi != oldi) {
      // loss delta over 4 dims/lane
      const short4 h4 = *(const short4*)(z_hi + (size_t)t * CDIM + lane * 4);
      const short4 l4 = *(const short4*)(z_lo + (size_t)t * CDIM + lane * 4);
      const float4 qn = *(const float4*)(cb + (size_t)newi * CDIM + lane * 4);
      const float4 qo = *(const float4*)(cb + (size_t)oldi * CDIM + lane * 4);
      const float zx = bf2f(h4.x) + bf2f(l4.x);
      const float zy = bf2f(h4.y) + bf2f(l4.y);
      const float zz = bf2f(h4.z) + bf2f(l4.z);
      const float zw = bf2f(h4.w) + bf2f(l4.w);
      float d = (qn.x - zx) * (qn.x - zx) - (qo.x - zx) * (qo.x - zx)
              + (qn.y - zy) * (qn.y - zy) - (qo.y - zy) * (qo.y - zy)
              + (qn.z - zz) * (qn.z - zz) - (qo.z - zz) * (qo.z - zz)
              + (qn.w - zw) * (qn.w - zw) - (qo.w - zw) * (qo.w - zw);
#pragma unroll
      for (int off = 32; off > 0; off >>= 1) d += __shfl_down(d, off, 64);
      if (lane == 0) {
        idxi[t] = newi;
        idx_f[t] = (float)newi;
        atomicAdd(loss, d * LOSS_SCALE);
      }
    }
  }
}

// ---------------- K3: proj_out MFMA (transposed): out[din][tok] ---------------
__global__ __launch_bounds__(256, 2) void k_proj_out_mfma(
    const short* __restrict__ wo_hi, const short* __restrict__ wo_lo,
    const short* __restrict__ cb_hi, const short* __restrict__ cb_lo,
    const int* __restrict__ idxi, const float* __restrict__ bout,
    float* __restrict__ out) {
  __shared__ short lds_s[4 * 128 * 32];
  char* ldsc = (char*)lds_s;
  const int tid = threadIdx.x;
  const int w = tid >> 6, lane = tid & 63;
  const int quad = lane >> 4, l16 = lane & 15;
  const int wm = w >> 1, wn = w & 1;
  const int tok0 = blockIdx.x * 128;
  const int din0 = blockIdx.y * 128;

  const int uA = (w << 6) + lane, uB = uA + 256;
  const int tA = uA >> 2, pA = uA & 3, qA = pA ^ ((tA >> 1) & 3);
  const int tB = uB >> 2, pB = uB & 3, qB = pB ^ ((tB >> 1) & 3);
  const short* gAh0 = wo_hi + (size_t)(din0 + tA) * CDIM + qA * 8;
  const short* gAh1 = wo_hi + (size_t)(din0 + tB) * CDIM + qB * 8;
  const short* gAl0 = wo_lo + (size_t)(din0 + tA) * CDIM + qA * 8;
  const short* gAl1 = wo_lo + (size_t)(din0 + tB) * CDIM + qB * 8;
  const int iA = idxi[tok0 + tA];
  const int iB = idxi[tok0 + tB];
  const short* gBh0 = cb_hi + (size_t)iA * CDIM + qA * 8;
  const short* gBh1 = cb_hi + (size_t)iB * CDIM + qB * 8;
  const short* gBl0 = cb_lo + (size_t)iA * CDIM + qA * 8;
  const short* gBl1 = cb_lo + (size_t)iB * CDIM + qB * 8;

  int aoffs[4], boffs[4];
#pragma unroll
  for (int mi = 0; mi < 4; ++mi) {
    const int t = wm * 64 + mi * 16 + l16;
    aoffs[mi] = t * 64 + (quad ^ ((t >> 1) & 3)) * 16;
  }
#pragma unroll
  for (int ni = 0; ni < 4; ++ni) {
    const int t = wn * 64 + ni * 16 + l16;
    boffs[ni] = 16384 + t * 64 + (quad ^ ((t >> 1) & 3)) * 16;
  }

  f32x4 acc[4][4];
#pragma unroll
  for (int mi = 0; mi < 4; ++mi)
#pragma unroll
    for (int ni = 0; ni < 4; ++ni) acc[mi][ni] = (f32x4){0.f, 0.f, 0.f, 0.f};

  for (int kb = 0; kb < CDIM; kb += 32) {
    __syncthreads();
    GLL16(gAh0 + kb, ldsc + ((0 * 4 + w) << 10));
    GLL16(gAh1 + kb, ldsc + ((1 * 4 + w) << 10));
    GLL16(gAl0 + kb, ldsc + ((2 * 4 + w) << 10));
    GLL16(gAl1 + kb, ldsc + ((3 * 4 + w) << 10));
    GLL16(gBh0 + kb, ldsc + ((4 * 4 + w) << 10));
    GLL16(gBh1 + kb, ldsc + ((5 * 4 + w) << 10));
    GLL16(gBl0 + kb, ldsc + ((6 * 4 + w) << 10));
    GLL16(gBl1 + kb, ldsc + ((7 * 4 + w) << 10));
    __syncthreads();
    bf16x8 ah[4], al[4], bh[4], bl[4];
#pragma unroll
    for (int mi = 0; mi < 4; ++mi) {
      ah[mi] = *(const bf16x8*)(ldsc + aoffs[mi]);
      al[mi] = *(const bf16x8*)(ldsc + 8192 + aoffs[mi]);
    }
#pragma unroll
    for (int ni = 0; ni < 4; ++ni) {
      bh[ni] = *(const bf16x8*)(ldsc + boffs[ni]);
      bl[ni] = *(const bf16x8*)(ldsc + 8192 + boffs[ni]);
    }
#pragma unroll
    for (int mi = 0; mi < 4; ++mi)
#pragma unroll
      for (int ni = 0; ni < 4; ++ni) {
        f32x4 c = acc[mi][ni];
        c = __builtin_amdgcn_mfma_f32_16x16x32_bf16(ah[mi], bh[ni], c, 0, 0, 0);
        c = __builtin_amdgcn_mfma_f32_16x16x32_bf16(ah[mi], bl[ni], c, 0, 0, 0);
        c = __builtin_amdgcn_mfma_f32_16x16x32_bf16(al[mi], bh[ni], c, 0, 0, 0);
        acc[mi][ni] = c;
      }
  }
  const int b = tok0 >> 10;
  const int hwb = tok0 & (HW - 1);
  float* ob = out + (size_t)b * DIN * HW;
#pragma unroll
  for (int mi = 0; mi < 4; ++mi)
#pragma unroll
    for (int r = 0; r < 4; ++r) {
      const int din = din0 + wm * 64 + mi * 16 + quad * 4 + r;
      const float bb = bout[din];
#pragma unroll
      for (int ni = 0; ni < 4; ++ni) {
        const int hw = hwb + wn * 64 + ni * 16 + l16;
        ob[(size_t)din * HW + hw] = acc[mi][ni][r] + bb;
      }
    }
}

extern "C" void kernel_launch(void* const* d_in, const int* in_sizes, int n_in,
                              void* d_out, int out_size, void* d_ws, size_t ws_size,
                              hipStream_t stream) {
  const float* x    = (const float*)d_in[0];
  const float* Win  = (const float*)d_in[1];
  const float* bin  = (const float*)d_in[2];
  const float* Wout = (const float*)d_in[3];
  const float* bout = (const float*)d_in[4];
  const float* cb   = (const float*)d_in[5];

  float* out   = (float*)d_out;
  float* idx_f = out + OUT_ELEMS;
  float* loss  = out + OUT_ELEMS + NTOK;

  char* w = (char*)d_ws;
  size_t off = 0;
  short* z_hi  = (short*)(w + off); off += (size_t)NTOK * CDIM * 2;
  short* z_lo  = (short*)(w + off); off += (size_t)NTOK * CDIM * 2;
  short* cb_hi = (short*)(w + off); off += (size_t)KCODES * CDIM * 2;
  short* cb_lo = (short*)(w + off); off += (size_t)KCODES * CDIM * 2;
  short* xT_hi = (short*)(w + off); off += (size_t)NTOK * DIN * 2;
  short* xT_lo = (short*)(w + off); off += (size_t)NTOK * DIN * 2;
  short* wi_hi = (short*)(w + off); off += (size_t)CDIM * DIN * 2;
  short* wi_lo = (short*)(w + off); off += (size_t)CDIM * DIN * 2;
  short* wo_hi = (short*)(w + off); off += (size_t)DIN * CDIM * 2;
  short* wo_lo = (short*)(w + off); off += (size_t)DIN * CDIM * 2;
  float* ee    = (float*)(w + off); off += (size_t)KCODES * 4;
  int*   idxi  = (int*)(w + off);   off += (size_t)NTOK * 4;
  float* pmv   = (float*)(w + off); off += (size_t)NPART * NTOK * 4;
  int*   pmi   = (int*)(w + off);   off += (size_t)NPART * NTOK * 4;
  float* psv   = (float*)(w + off); off += (size_t)NPART * NTOK * 4;
  int*   rlist = (int*)(w + off);   off += (size_t)MAXR * 4;
  int*   rcount= (int*)(w + off);   off += 256;
  double* slotv= (double*)(w + off);off += (size_t)MAXR * RCHUNK * 8;
  int*   sloti = (int*)(w + off);   off += (size_t)MAXR * RCHUNK * 4;

  k_prep        <<<dim3(PREP_CB_BLKS + PREP_W_BLKS + PREP_X_BLKS),
                   dim3(256), 0, stream>>>(cb, Win, Wout, x, cb_hi, cb_lo, ee,
                                           wi_hi, wi_lo, wo_hi, wo_lo,
                                           xT_hi, xT_lo, loss, rcount);
  k_proj_in_mfma<<<dim3(NTOK / 128, CDIM / 128), dim3(256), 0, stream>>>(
      xT_hi, xT_lo, wi_hi, wi_lo, bin, z_hi, z_lo);
  k_argmin_mfma <<<dim3(NTOK / 128, NSTRIP), dim3(256), 0, stream>>>(
      z_hi, z_lo, cb_hi, cb_lo, ee, pmv, pmi, psv);
  k_merge_loss  <<<dim3(NTOK / 4), dim3(256), 0, stream>>>(
      pmv, pmi, psv, z_hi, z_lo, cb, idxi, idx_f, rlist, rcount, loss);
  k_rescue_chunk<<<dim3(RBLOCKS), dim3(256), 0, stream>>>(
      z_hi, z_lo, cb, rlist, rcount, slotv, sloti);
  k_rescue_fin  <<<dim3(1), dim3(256), 0, stream>>>(
      slotv, sloti, rlist, rcount, z_hi, z_lo, cb, idxi, idx_f, loss);
  k_proj_out_mfma<<<dim3(NTOK / 128, DIN / 128), dim3(256), 0, stream>>>(
      wo_hi, wo_lo, cb_hi, cb_lo, idxi, bout, out);
}